// Round 1
// baseline (7925.797 us; speedup 1.0000x reference)
//
#include <hip/hip_runtime.h>
#include <hip/hip_bf16.h>

#define BQ 512
#define LQ 100
#define HQ 256
#define GQ 768
#define WINQ 5
#define MQ 95   // L - WIN

typedef __hip_bfloat16 bf16;

__device__ __forceinline__ float bf2f(bf16 v) { return __bfloat162float(v); }
__device__ __forceinline__ bf16 f2bf(float v) { return __float2bfloat16(v); }
__device__ __forceinline__ float sigmf(float x) { return 1.0f / (1.0f + __expf(-x)); }
__device__ __forceinline__ float tanh_fast(float x) {
  float ax = fabsf(x);
  float e = __expf(-2.0f * ax);
  float t = (1.0f - e) / (1.0f + e);
  return copysignf(t, x);
}
__device__ __forceinline__ float dot4(float4 a, float4 b) {
  return fmaf(a.x, b.x, fmaf(a.y, b.y, fmaf(a.z, b.z, a.w * b.w)));
}

// ---------------- layer-0 scan: x(B,L,3) -> out(B,L,256), both receivers ----
template<int M>
__global__ __launch_bounds__(256) void scan0_kernel(
    const float* __restrict__ x,
    const float* __restrict__ WihA, const float* __restrict__ WhhA,
    const float* __restrict__ bihA, const float* __restrict__ bhhA,
    const float* __restrict__ WihB, const float* __restrict__ WhhB,
    const float* __restrict__ bihB, const float* __restrict__ bhhB,
    bf16* __restrict__ outA, bf16* __restrict__ outB) {
  const int r = blockIdx.y;
  const float* Wih = r ? WihB : WihA;
  const float* Whh = r ? WhhB : WhhA;
  const float* bih = r ? bihB : bihA;
  const float* bhh = r ? bhhB : bhhA;
  bf16* out = r ? outB : outA;
  const int b0 = blockIdx.x * M;
  const int j = threadIdx.x;  // hidden column 0..255

  __shared__ float hl[M][HQ];
  __shared__ float xl[M][4];

  #pragma unroll
  for (int m = 0; m < M; ++m) hl[m][j] = 0.0f;

  float wxr[3], wxz[3], wxn[3];
  #pragma unroll
  for (int i = 0; i < 3; ++i) {
    wxr[i] = Wih[(size_t)j * 3 + i];
    wxz[i] = Wih[(size_t)(j + HQ) * 3 + i];
    wxn[i] = Wih[(size_t)(j + 2 * HQ) * 3 + i];
  }
  const float bxr = bih[j], bxz = bih[j + HQ], bxn = bih[j + 2 * HQ];
  const float bhr = bhh[j], bhz = bhh[j + HQ], bhn = bhh[j + 2 * HQ];
  const float4* wr4 = reinterpret_cast<const float4*>(Whh + (size_t)j * HQ);
  const float4* wz4 = reinterpret_cast<const float4*>(Whh + (size_t)(j + HQ) * HQ);
  const float4* wn4 = reinterpret_cast<const float4*>(Whh + (size_t)(j + 2 * HQ) * HQ);

  for (int t = 0; t < LQ; ++t) {
    if (j < M * 3) {
      int m = j / 3, i = j - m * 3;
      xl[m][i] = x[((size_t)(b0 + m) * LQ + t) * 3 + i];
    }
    __syncthreads();
    float ar[M], az[M], an[M];
    #pragma unroll
    for (int m = 0; m < M; ++m) { ar[m] = bhr; az[m] = bhz; an[m] = bhn; }
    #pragma unroll 2
    for (int k4 = 0; k4 < HQ / 4; ++k4) {
      const float4 wr = wr4[k4], wz = wz4[k4], wn = wn4[k4];
      #pragma unroll
      for (int m = 0; m < M; ++m) {
        const float4 hv = *reinterpret_cast<const float4*>(&hl[m][k4 * 4]);
        ar[m] = fmaf(hv.x, wr.x, fmaf(hv.y, wr.y, fmaf(hv.z, wr.z, fmaf(hv.w, wr.w, ar[m]))));
        az[m] = fmaf(hv.x, wz.x, fmaf(hv.y, wz.y, fmaf(hv.z, wz.z, fmaf(hv.w, wz.w, az[m]))));
        an[m] = fmaf(hv.x, wn.x, fmaf(hv.y, wn.y, fmaf(hv.z, wn.z, fmaf(hv.w, wn.w, an[m]))));
      }
    }
    float hnew[M];
    #pragma unroll
    for (int m = 0; m < M; ++m) {
      const float hold = hl[m][j];
      const float xr = fmaf(wxr[0], xl[m][0], fmaf(wxr[1], xl[m][1], fmaf(wxr[2], xl[m][2], bxr)));
      const float xz = fmaf(wxz[0], xl[m][0], fmaf(wxz[1], xl[m][1], fmaf(wxz[2], xl[m][2], bxz)));
      const float xn = fmaf(wxn[0], xl[m][0], fmaf(wxn[1], xl[m][1], fmaf(wxn[2], xl[m][2], bxn)));
      const float rg = sigmf(xr + ar[m]);
      const float zg = sigmf(xz + az[m]);
      const float ng = tanh_fast(fmaf(rg, an[m], xn));
      hnew[m] = fmaf(zg, hold - ng, ng);  // (1-z)*n + z*h
    }
    __syncthreads();
    #pragma unroll
    for (int m = 0; m < M; ++m) {
      hl[m][j] = hnew[m];
      out[((size_t)(b0 + m) * LQ + t) * HQ + j] = f2bf(hnew[m]);
    }
  }
}

// ------- layer-1 scan with fused input projection (in bf16 -> out bf16) ----
template<int M>
__global__ __launch_bounds__(256) void scan1_kernel(
    const bf16* __restrict__ inA, const bf16* __restrict__ inB,
    const float* __restrict__ WihA, const float* __restrict__ WhhA,
    const float* __restrict__ bihA, const float* __restrict__ bhhA,
    const float* __restrict__ WihB, const float* __restrict__ WhhB,
    const float* __restrict__ bihB, const float* __restrict__ bhhB,
    bf16* __restrict__ outA, bf16* __restrict__ outB) {
  const int r = blockIdx.y;
  const bf16* inp = r ? inB : inA;
  const float* Wih = r ? WihB : WihA;
  const float* Whh = r ? WhhB : WhhA;
  const float* bih = r ? bihB : bihA;
  const float* bhh = r ? bhhB : bhhA;
  bf16* out = r ? outB : outA;
  const int b0 = blockIdx.x * M;
  const int j = threadIdx.x;

  __shared__ float hl[M][HQ];
  __shared__ float xv[M][HQ];

  #pragma unroll
  for (int m = 0; m < M; ++m) hl[m][j] = 0.0f;

  const float bxr = bih[j], bxz = bih[j + HQ], bxn = bih[j + 2 * HQ];
  const float bhr = bhh[j], bhz = bhh[j + HQ], bhn = bhh[j + 2 * HQ];
  const float4* whr4 = reinterpret_cast<const float4*>(Whh + (size_t)j * HQ);
  const float4* whz4 = reinterpret_cast<const float4*>(Whh + (size_t)(j + HQ) * HQ);
  const float4* whn4 = reinterpret_cast<const float4*>(Whh + (size_t)(j + 2 * HQ) * HQ);
  const float4* wxr4 = reinterpret_cast<const float4*>(Wih + (size_t)j * HQ);
  const float4* wxz4 = reinterpret_cast<const float4*>(Wih + (size_t)(j + HQ) * HQ);
  const float4* wxn4 = reinterpret_cast<const float4*>(Wih + (size_t)(j + 2 * HQ) * HQ);

  for (int t = 0; t < LQ; ++t) {
    for (int idx = j; idx < M * HQ; idx += 256) {
      int m = idx >> 8, k = idx & (HQ - 1);
      xv[m][k] = bf2f(inp[((size_t)(b0 + m) * LQ + t) * HQ + k]);
    }
    __syncthreads();
    float ar[M], az[M], an[M], xr[M], xz[M], xn[M];
    #pragma unroll
    for (int m = 0; m < M; ++m) {
      ar[m] = bhr; az[m] = bhz; an[m] = bhn;
      xr[m] = bxr; xz[m] = bxz; xn[m] = bxn;
    }
    #pragma unroll 2
    for (int k4 = 0; k4 < HQ / 4; ++k4) {
      const float4 wr = whr4[k4], wz = whz4[k4], wn = whn4[k4];
      const float4 vr = wxr4[k4], vz = wxz4[k4], vn = wxn4[k4];
      #pragma unroll
      for (int m = 0; m < M; ++m) {
        const float4 hv = *reinterpret_cast<const float4*>(&hl[m][k4 * 4]);
        const float4 xw = *reinterpret_cast<const float4*>(&xv[m][k4 * 4]);
        ar[m] += dot4(hv, wr);
        az[m] += dot4(hv, wz);
        an[m] += dot4(hv, wn);
        xr[m] += dot4(xw, vr);
        xz[m] += dot4(xw, vz);
        xn[m] += dot4(xw, vn);
      }
    }
    float hnew[M];
    #pragma unroll
    for (int m = 0; m < M; ++m) {
      const float hold = hl[m][j];
      const float rg = sigmf(xr[m] + ar[m]);
      const float zg = sigmf(xz[m] + az[m]);
      const float ng = tanh_fast(fmaf(rg, an[m], xn[m]));
      hnew[m] = fmaf(zg, hold - ng, ng);
    }
    __syncthreads();
    #pragma unroll
    for (int m = 0; m < M; ++m) {
      hl[m][j] = hnew[m];
      out[((size_t)(b0 + m) * LQ + t) * HQ + j] = f2bf(hnew[m]);
    }
  }
}

// ---------------- q/e projections: one wave per (branch,b,l) ---------------
__global__ __launch_bounds__(256) void qe_kernel(
    const bf16* __restrict__ out1, const bf16* __restrict__ out2,
    const float* __restrict__ attn_w,
    float* __restrict__ q1, float* __restrict__ e1,
    float* __restrict__ q2, float* __restrict__ e2) {
  const int wid = blockIdx.x * 4 + (threadIdx.x >> 6);
  const int lane = threadIdx.x & 63;
  const int br = wid / (BQ * LQ);
  const int bl = wid - br * (BQ * LQ);
  const bf16* row = (br ? out2 : out1) + (size_t)bl * HQ;
  float sq = 0.f, se = 0.f;
  #pragma unroll
  for (int jj = 0; jj < 4; ++jj) {
    int h = lane + jj * 64;
    float v = bf2f(row[h]);
    sq = fmaf(v, attn_w[h], sq);
    se = fmaf(v, attn_w[HQ + h], se);
  }
  #pragma unroll
  for (int o = 32; o > 0; o >>= 1) { sq += __shfl_down(sq, o); se += __shfl_down(se, o); }
  if (lane == 0) {
    (br ? q2 : q1)[bl] = sq;
    (br ? e2 : e1)[bl] = se;
  }
}

// ---------------- softmax + windowed context c -----------------------------
__global__ __launch_bounds__(256) void attnc_kernel(
    const bf16* __restrict__ out1, const bf16* __restrict__ out2,
    const float* __restrict__ q1, const float* __restrict__ e1,
    const float* __restrict__ q2, const float* __restrict__ e2,
    bf16* __restrict__ c1, bf16* __restrict__ c2) {
  const int b = blockIdx.x;
  const int br = blockIdx.y;
  const bf16* out = br ? out2 : out1;
  const float* q = br ? q2 : q1;
  const float* e = br ? e2 : e1;
  bf16* cb = br ? c2 : c1;
  const int h = threadIdx.x;
  for (int m = 0; m < MQ; ++m) {
    const float qq = q[b * LQ + m + WINQ];
    float s[WINQ];
    float mx = -1e30f;
    #pragma unroll
    for (int w = 0; w < WINQ; ++w) { s[w] = qq + e[b * LQ + m + w]; mx = fmaxf(mx, s[w]); }
    float sum = 0.f;
    #pragma unroll
    for (int w = 0; w < WINQ; ++w) { s[w] = __expf(s[w] - mx); sum += s[w]; }
    const float inv = 1.0f / sum;
    float accv = 0.f;
    #pragma unroll
    for (int w = 0; w < WINQ; ++w)
      accv = fmaf(s[w], bf2f(out[((size_t)b * LQ + m + w) * HQ + h]), accv);
    cb[((size_t)b * MQ + m) * HQ + h] = f2bf(accv * inv);
  }
}

// ------- fused FC: fused[i,o] = b[o] + c[i,:]·W[o,:256] + out[i+5,:]·W[o,256:]
__global__ __launch_bounds__(256) void fcgemm_kernel(
    const bf16* __restrict__ c1, const bf16* __restrict__ c2,
    const bf16* __restrict__ out1, const bf16* __restrict__ out2,
    const float* __restrict__ fcW, const float* __restrict__ fcb,
    bf16* __restrict__ f1, bf16* __restrict__ f2) {
  const int br = blockIdx.y;
  const bf16* cb = br ? c2 : c1;
  const bf16* out = br ? out2 : out1;
  bf16* fo = br ? f2 : f1;
  const int i0 = blockIdx.x * 32;
  const int tid = threadIdx.x;  // output column o
  __shared__ float l1[32][128];
  __shared__ float l2[32][128];
  float acc[32];
  #pragma unroll
  for (int i = 0; i < 32; ++i) acc[i] = 0.0f;
  const float4* wrow = reinterpret_cast<const float4*>(fcW + (size_t)tid * 512);
  for (int kh = 0; kh < 2; ++kh) {
    __syncthreads();
    for (int idx = tid; idx < 32 * 128; idx += 256) {
      int rr = idx >> 7, k = idx & 127;
      int gi = i0 + rr;
      int bb = gi / 95;
      int mm = gi - bb * 95;
      l1[rr][k] = bf2f(cb[(size_t)gi * HQ + kh * 128 + k]);
      l2[rr][k] = bf2f(out[((size_t)bb * LQ + mm + WINQ) * HQ + kh * 128 + k]);
    }
    __syncthreads();
    #pragma unroll 4
    for (int k4 = 0; k4 < 32; ++k4) {
      const float4 w1 = wrow[kh * 32 + k4];
      const float4 w2 = wrow[64 + kh * 32 + k4];
      #pragma unroll
      for (int i = 0; i < 32; ++i) {
        const float4 a1 = *reinterpret_cast<const float4*>(&l1[i][k4 * 4]);
        const float4 a2 = *reinterpret_cast<const float4*>(&l2[i][k4 * 4]);
        acc[i] += dot4(a1, w1) + dot4(a2, w2);
      }
    }
  }
  const float bo = fcb[tid];
  for (int i = 0; i < 32; ++i)
    fo[(size_t)(i0 + i) * HQ + tid] = f2bf(acc[i] + bo);
}

// ---------------- final head: one wave per (b,l) ---------------------------
__global__ __launch_bounds__(256) void final_kernel(
    const bf16* __restrict__ out1,
    const bf16* __restrict__ f1, const bf16* __restrict__ f2,
    const float* __restrict__ outW, const float* __restrict__ outb,
    float* __restrict__ dout) {
  const int wid = blockIdx.x * 4 + (threadIdx.x >> 6);
  const int lane = threadIdx.x & 63;
  const int b = wid / LQ, l = wid - b * LQ;
  const bf16* s1 = (l < WINQ) ? (out1 + ((size_t)b * LQ + l) * HQ)
                              : (f1 + ((size_t)b * MQ + (l - WINQ)) * HQ);
  int l2 = l + 10;  // D = 10
  if (l2 > LQ - 1) l2 = LQ - 1;
  const bf16* s2 = f2 + ((size_t)b * MQ + (l2 - WINQ)) * HQ;
  float s = 0.0f;
  #pragma unroll
  for (int jj = 0; jj < 4; ++jj) {
    int h = lane + jj * 64;
    s = fmaf(bf2f(s1[h]), outW[h], s);
    s = fmaf(bf2f(s2[h]), outW[HQ + h], s);
  }
  #pragma unroll
  for (int o = 32; o > 0; o >>= 1) s += __shfl_down(s, o);
  if (lane == 0) dout[wid] = sigmf(s + outb[0]);
}

extern "C" void kernel_launch(void* const* d_in, const int* in_sizes, int n_in,
                              void* d_out, int out_size, void* d_ws, size_t ws_size,
                              hipStream_t stream) {
  const float* x       = (const float*)d_in[0];
  const float* r1_Wih0 = (const float*)d_in[1];
  const float* r1_Whh0 = (const float*)d_in[2];
  const float* r1_bih0 = (const float*)d_in[3];
  const float* r1_bhh0 = (const float*)d_in[4];
  const float* r1_Wih1 = (const float*)d_in[5];
  const float* r1_Whh1 = (const float*)d_in[6];
  const float* r1_bih1 = (const float*)d_in[7];
  const float* r1_bhh1 = (const float*)d_in[8];
  const float* r2_Wih0 = (const float*)d_in[9];
  const float* r2_Whh0 = (const float*)d_in[10];
  const float* r2_bih0 = (const float*)d_in[11];
  const float* r2_bhh0 = (const float*)d_in[12];
  const float* r2_Wih1 = (const float*)d_in[13];
  const float* r2_Whh1 = (const float*)d_in[14];
  const float* r2_bih1 = (const float*)d_in[15];
  const float* r2_bhh1 = (const float*)d_in[16];
  const float* attn_w  = (const float*)d_in[17];
  const float* fc_W    = (const float*)d_in[18];
  const float* fc_b    = (const float*)d_in[19];
  const float* out_W   = (const float*)d_in[20];
  const float* out_b   = (const float*)d_in[21];

  char* p = (char*)d_ws;
  auto carve = [&](size_t bytes) {
    char* r = p;
    p += ((bytes + 255) / 256) * 256;
    return r;
  };
  const size_t SEQ = (size_t)BQ * LQ * HQ;   // 13,107,200 elems
  const size_t FSEQ = (size_t)BQ * MQ * HQ;  // 12,451,840 elems
  bf16* o01 = (bf16*)carve(SEQ * 2);   // r1 layer-0 out; later aliased as c1
  bf16* o02 = (bf16*)carve(SEQ * 2);   // r2 layer-0 out; later aliased as c2
  bf16* o11 = (bf16*)carve(SEQ * 2);   // r1 layer-1 out (out1)
  bf16* o12 = (bf16*)carve(SEQ * 2);   // r2 layer-1 out (out2)
  bf16* f1  = (bf16*)carve(FSEQ * 2);  // fused branch-1
  bf16* f2  = (bf16*)carve(FSEQ * 2);  // fused branch-2
  float* q1 = (float*)carve((size_t)BQ * LQ * 4);
  float* e1 = (float*)carve((size_t)BQ * LQ * 4);
  float* q2 = (float*)carve((size_t)BQ * LQ * 4);
  float* e2 = (float*)carve((size_t)BQ * LQ * 4);
  bf16* c1 = o01;  // o01 dead after scan1 -> reuse for context buffer
  bf16* c2 = o02;

  constexpr int M = 4;
  scan0_kernel<M><<<dim3(BQ / M, 2), 256, 0, stream>>>(
      x, r1_Wih0, r1_Whh0, r1_bih0, r1_bhh0,
      r2_Wih0, r2_Whh0, r2_bih0, r2_bhh0, o01, o02);
  scan1_kernel<M><<<dim3(BQ / M, 2), 256, 0, stream>>>(
      o01, o02, r1_Wih1, r1_Whh1, r1_bih1, r1_bhh1,
      r2_Wih1, r2_Whh1, r2_bih1, r2_bhh1, o11, o12);
  qe_kernel<<<(2 * BQ * LQ) / 4, 256, 0, stream>>>(o11, o12, attn_w, q1, e1, q2, e2);
  attnc_kernel<<<dim3(BQ, 2), 256, 0, stream>>>(o11, o12, q1, e1, q2, e2, c1, c2);
  fcgemm_kernel<<<dim3((BQ * MQ) / 32, 2), 256, 0, stream>>>(c1, c2, o11, o12, fc_W, fc_b, f1, f2);
  final_kernel<<<(BQ * LQ) / 4, 256, 0, stream>>>(o11, f1, f2, out_W, out_b, (float*)d_out);
}

// Round 2
// 3895.677 us; speedup vs baseline: 2.0345x; 2.0345x over previous
//
#include <hip/hip_runtime.h>
#include <hip/hip_bf16.h>

#define BQ 512
#define LQ 100
#define HQ 256
#define GQ 768
#define WINQ 5
#define MQ 95   // L - WIN
#define HPAD 264   // 256 + 8 pad: 528B row stride -> 2-way-max LDS bank aliasing on b128

typedef __hip_bfloat16 bf16;
typedef unsigned short u16;
typedef __attribute__((ext_vector_type(8))) short short8;
typedef __attribute__((ext_vector_type(4))) float f32x4;

__device__ __forceinline__ float bf2f(bf16 v) { return __bfloat162float(v); }
__device__ __forceinline__ bf16 f2bf(float v) { return __float2bfloat16(v); }
__device__ __forceinline__ u16 f2bfb(float v) { return __builtin_bit_cast(u16, __float2bfloat16(v)); }
__device__ __forceinline__ float bfb2f(u16 u) {
  unsigned int x = ((unsigned int)u) << 16;
  return __builtin_bit_cast(float, x);
}
__device__ __forceinline__ float sigmf(float x) { return 1.0f / (1.0f + __expf(-x)); }
__device__ __forceinline__ float tanh_fast(float x) {
  float ax = fabsf(x);
  float e = __expf(-2.0f * ax);
  float t = (1.0f - e) / (1.0f + e);
  return copysignf(t, x);
}
__device__ __forceinline__ short8 ld8(const u16* p) { return *(const short8*)p; }
__device__ __forceinline__ f32x4 mfma16(short8 a, short8 b, f32x4 c) {
  return __builtin_amdgcn_mfma_f32_16x16x32_bf16(a, b, c, 0, 0, 0);
}

// ---------------- fp32 -> bf16 weight conversion ---------------------------
__global__ __launch_bounds__(256) void cvt_kernel(const float* __restrict__ src,
                                                  u16* __restrict__ dst, int n4) {
  int i = blockIdx.x * 256 + threadIdx.x;
  if (i < n4) {
    float4 v = reinterpret_cast<const float4*>(src)[i];
    ushort4 o;
    o.x = f2bfb(v.x); o.y = f2bfb(v.y); o.z = f2bfb(v.z); o.w = f2bfb(v.w);
    reinterpret_cast<ushort4*>(dst)[i] = o;
  }
}

// ---------------- xw0: x(B,L,3) @ Wih0^T + bih0 -> bf16 [row][768] ---------
__global__ __launch_bounds__(256) void xw0_kernel(
    const float* __restrict__ x,
    const float* __restrict__ WihA, const float* __restrict__ bihA,
    const float* __restrict__ WihB, const float* __restrict__ bihB,
    u16* __restrict__ xw) {
  const int row = blockIdx.x;            // b*L + t
  const int r = blockIdx.y;
  const float* Wih = r ? WihB : WihA;
  const float* bih = r ? bihB : bihA;
  u16* o = xw + (size_t)r * BQ * LQ * GQ + (size_t)row * GQ;
  const float x0 = x[(size_t)row * 3];
  const float x1 = x[(size_t)row * 3 + 1];
  const float x2 = x[(size_t)row * 3 + 2];
  for (int g = threadIdx.x; g < GQ; g += 256) {
    float v = fmaf(x0, Wih[g * 3], fmaf(x1, Wih[g * 3 + 1], fmaf(x2, Wih[g * 3 + 2], bih[g])));
    o[g] = f2bfb(v);
  }
}

// ---------------- xw1: o0(51200,256)bf16 @ Wih1^T + bih1 -> bf16 -----------
__global__ __launch_bounds__(256) void xw1_gemm_kernel(
    const u16* __restrict__ o0A, const u16* __restrict__ o0B,
    const u16* __restrict__ wihA, const u16* __restrict__ wihB,
    const float* __restrict__ bihA, const float* __restrict__ bihB,
    u16* __restrict__ xw) {
  const int r = blockIdx.y;
  const u16* A = r ? o0B : o0A;
  const u16* Wih = r ? wihB : wihA;
  const float* bih = r ? bihB : bihA;
  u16* out = xw + (size_t)r * BQ * LQ * GQ;
  const int row0 = blockIdx.x * 64;
  const int tid = threadIdx.x;
  const int w = tid >> 6, lane = tid & 63, l15 = lane & 15, quad = lane >> 4;

  __shared__ u16 a_lds[64][HPAD];
  for (int g = tid; g < 64 * 32; g += 256) {           // 16B groups
    int rr = g >> 5, c8 = (g & 31) * 8;
    *(short8*)&a_lds[rr][c8] = ld8(&A[(size_t)(row0 + rr) * HQ + c8]);
  }
  __syncthreads();

  for (int nt = 0; nt < 12; ++nt) {
    const int n0 = w * 192 + nt * 16;
    const u16* bp = Wih + (size_t)(n0 + l15) * HQ + quad * 8;
    short8 b[8];
    #pragma unroll
    for (int kt = 0; kt < 8; ++kt) b[kt] = ld8(bp + kt * 32);
    const float bias = bih[n0 + l15];
    #pragma unroll
    for (int mt = 0; mt < 4; ++mt) {
      f32x4 acc = {bias, bias, bias, bias};
      #pragma unroll
      for (int kt = 0; kt < 8; ++kt) {
        short8 a = ld8(&a_lds[mt * 16 + l15][kt * 32 + quad * 8]);
        acc = mfma16(a, b[kt], acc);
      }
      #pragma unroll
      for (int reg = 0; reg < 4; ++reg) {
        int row = row0 + mt * 16 + quad * 4 + reg;
        out[(size_t)row * GQ + n0 + l15] = f2bfb(acc[reg]);
      }
    }
  }
}

// ---------------- MFMA streaming GRU scan ----------------------------------
// Block: 256 thr (4 waves), 16 batch rows. Wave w owns hidden cols [w*64,w*64+64).
// h(t) feedback: bf16 in LDS (double buffer) for MFMA A; fp32 carry in regs.
__global__ __launch_bounds__(256) void scan_mfma_kernel(
    const u16* __restrict__ xwA, const u16* __restrict__ xwB,
    const u16* __restrict__ whhA, const u16* __restrict__ whhB,
    const float* __restrict__ bhhA, const float* __restrict__ bhhB,
    u16* __restrict__ outA, u16* __restrict__ outB) {
  const int r = blockIdx.y;
  const u16* xw = r ? xwB : xwA;
  const u16* whh = r ? whhB : whhA;
  const float* bhh = r ? bhhB : bhhA;
  u16* out = r ? outB : outA;
  const int b0 = blockIdx.x * 16;
  const int tid = threadIdx.x;
  const int w = tid >> 6, lane = tid & 63, l15 = lane & 15, quad = lane >> 4;
  const int jbase = w * 64;

  __shared__ u16 h_lds[2][16][HPAD];
  for (int i = tid; i < 16 * HPAD; i += 256)
    h_lds[0][i / HPAD][i % HPAD] = 0;

  // biases for this wave's 12 N-tiles (n = g*256 + jbase + jt*16 + l15)
  float bh[3][4];
  #pragma unroll
  for (int g = 0; g < 3; ++g)
    #pragma unroll
    for (int jt = 0; jt < 4; ++jt)
      bh[g][jt] = bhh[g * HQ + jbase + jt * 16 + l15];

  // per-thread fp32 h carry at its 16 (m=quad*4+reg, j=jbase+jt*16+l15) cells
  float hreg[4][4];
  #pragma unroll
  for (int jt = 0; jt < 4; ++jt)
    #pragma unroll
    for (int reg = 0; reg < 4; ++reg) hreg[jt][reg] = 0.0f;

  size_t rowoff[4];
  #pragma unroll
  for (int reg = 0; reg < 4; ++reg)
    rowoff[reg] = (size_t)(b0 + quad * 4 + reg) * LQ * GQ;

  __syncthreads();

  for (int t = 0; t < LQ; ++t) {
    const int rb = t & 1, wb = rb ^ 1;

    // xw for this step (consumed in epilogue -> latency hidden by MFMA stream)
    u16 xv[3][4][4];
    #pragma unroll
    for (int g = 0; g < 3; ++g)
      #pragma unroll
      for (int jt = 0; jt < 4; ++jt) {
        const int col = g * HQ + jbase + jt * 16 + l15;
        #pragma unroll
        for (int reg = 0; reg < 4; ++reg)
          xv[g][jt][reg] = xw[rowoff[reg] + (size_t)t * GQ + col];
      }

    // A fragments from LDS h(t)
    short8 a[8];
    #pragma unroll
    for (int kt = 0; kt < 8; ++kt)
      a[kt] = ld8(&h_lds[rb][l15][kt * 32 + quad * 8]);

    f32x4 acc[3][4];
    #pragma unroll
    for (int g = 0; g < 3; ++g)
      #pragma unroll
      for (int jt = 0; jt < 4; ++jt) {
        float bv = bh[g][jt];
        acc[g][jt] = f32x4{bv, bv, bv, bv};
      }

    // gates = h @ Whh^T (+bhh), streamed B from L2
    #pragma unroll
    for (int g = 0; g < 3; ++g)
      #pragma unroll 2
      for (int jt = 0; jt < 4; ++jt) {
        const u16* bp = whh + (size_t)(g * HQ + jbase + jt * 16 + l15) * HQ + quad * 8;
        #pragma unroll
        for (int kt = 0; kt < 8; ++kt)
          acc[g][jt] = mfma16(a[kt], ld8(bp + kt * 32), acc[g][jt]);
      }

    // epilogue: gate math + h update (fp32 carry in hreg)
    #pragma unroll
    for (int jt = 0; jt < 4; ++jt) {
      const int j = jbase + jt * 16 + l15;
      #pragma unroll
      for (int reg = 0; reg < 4; ++reg) {
        const int m = quad * 4 + reg;
        const float rg = sigmf(acc[0][jt][reg] + bfb2f(xv[0][jt][reg]));
        const float zg = sigmf(acc[1][jt][reg] + bfb2f(xv[1][jt][reg]));
        const float ng = tanh_fast(fmaf(rg, acc[2][jt][reg], bfb2f(xv[2][jt][reg])));
        const float hn = fmaf(zg, hreg[jt][reg] - ng, ng);
        hreg[jt][reg] = hn;
        const u16 hb = f2bfb(hn);
        h_lds[wb][m][j] = hb;
        out[((size_t)(b0 + m) * LQ + t) * HQ + j] = hb;
      }
    }
    __syncthreads();
  }
}

// ---------------- q/e projections ------------------------------------------
__global__ __launch_bounds__(256) void qe_kernel(
    const bf16* __restrict__ out1, const bf16* __restrict__ out2,
    const float* __restrict__ attn_w,
    float* __restrict__ q1, float* __restrict__ e1,
    float* __restrict__ q2, float* __restrict__ e2) {
  const int wid = blockIdx.x * 4 + (threadIdx.x >> 6);
  const int lane = threadIdx.x & 63;
  const int br = wid / (BQ * LQ);
  const int bl = wid - br * (BQ * LQ);
  const bf16* row = (br ? out2 : out1) + (size_t)bl * HQ;
  float sq = 0.f, se = 0.f;
  #pragma unroll
  for (int jj = 0; jj < 4; ++jj) {
    int h = lane + jj * 64;
    float v = bf2f(row[h]);
    sq = fmaf(v, attn_w[h], sq);
    se = fmaf(v, attn_w[HQ + h], se);
  }
  #pragma unroll
  for (int o = 32; o > 0; o >>= 1) { sq += __shfl_down(sq, o); se += __shfl_down(se, o); }
  if (lane == 0) {
    (br ? q2 : q1)[bl] = sq;
    (br ? e2 : e1)[bl] = se;
  }
}

// ---------------- softmax + windowed context c -----------------------------
__global__ __launch_bounds__(256) void attnc_kernel(
    const bf16* __restrict__ out1, const bf16* __restrict__ out2,
    const float* __restrict__ q1, const float* __restrict__ e1,
    const float* __restrict__ q2, const float* __restrict__ e2,
    bf16* __restrict__ c1, bf16* __restrict__ c2) {
  const int b = blockIdx.x;
  const int br = blockIdx.y;
  const bf16* out = br ? out2 : out1;
  const float* q = br ? q2 : q1;
  const float* e = br ? e2 : e1;
  bf16* cb = br ? c2 : c1;
  const int h = threadIdx.x;
  for (int m = 0; m < MQ; ++m) {
    const float qq = q[b * LQ + m + WINQ];
    float s[WINQ];
    float mx = -1e30f;
    #pragma unroll
    for (int wv = 0; wv < WINQ; ++wv) { s[wv] = qq + e[b * LQ + m + wv]; mx = fmaxf(mx, s[wv]); }
    float sum = 0.f;
    #pragma unroll
    for (int wv = 0; wv < WINQ; ++wv) { s[wv] = __expf(s[wv] - mx); sum += s[wv]; }
    const float inv = 1.0f / sum;
    float accv = 0.f;
    #pragma unroll
    for (int wv = 0; wv < WINQ; ++wv)
      accv = fmaf(s[wv], bf2f(out[((size_t)b * LQ + m + wv) * HQ + h]), accv);
    cb[((size_t)b * MQ + m) * HQ + h] = f2bf(accv * inv);
  }
}

// ---------------- fused FC via MFMA: [c | out] @ fcW^T + fcb ---------------
__global__ __launch_bounds__(256) void fc_mfma_kernel(
    const u16* __restrict__ c1, const u16* __restrict__ c2,
    const u16* __restrict__ o1, const u16* __restrict__ o2,
    const u16* __restrict__ fcw, const float* __restrict__ fcb,
    u16* __restrict__ f1, u16* __restrict__ f2) {
  const int br = blockIdx.y;
  const u16* cb = br ? c2 : c1;
  const u16* ob = br ? o2 : o1;
  u16* fo = br ? f2 : f1;
  const int i0 = blockIdx.x * 64;
  const int tid = threadIdx.x;
  const int w = tid >> 6, lane = tid & 63, l15 = lane & 15, quad = lane >> 4;

  __shared__ u16 a_lds[64][520];
  for (int g = tid; g < 64 * 64; g += 256) {        // 16B groups, K=512
    int rr = g >> 6, c8 = (g & 63) * 8;
    int gi = i0 + rr;
    int bb = gi / MQ, mm = gi - bb * MQ;
    const u16* src = (c8 < HQ) ? &cb[(size_t)gi * HQ + c8]
                               : &ob[((size_t)bb * LQ + mm + WINQ) * HQ + (c8 - HQ)];
    *(short8*)&a_lds[rr][c8] = ld8(src);
  }
  __syncthreads();

  for (int nt = 0; nt < 4; ++nt) {
    const int n0 = w * 64 + nt * 16;
    const u16* bp = fcw + (size_t)(n0 + l15) * 512 + quad * 8;
    short8 b[16];
    #pragma unroll
    for (int kt = 0; kt < 16; ++kt) b[kt] = ld8(bp + kt * 32);
    const float bias = fcb[n0 + l15];
    #pragma unroll
    for (int mt = 0; mt < 4; ++mt) {
      f32x4 acc = {bias, bias, bias, bias};
      #pragma unroll
      for (int kt = 0; kt < 16; ++kt) {
        short8 a = ld8(&a_lds[mt * 16 + l15][kt * 32 + quad * 8]);
        acc = mfma16(a, b[kt], acc);
      }
      #pragma unroll
      for (int reg = 0; reg < 4; ++reg)
        fo[(size_t)(i0 + mt * 16 + quad * 4 + reg) * HQ + n0 + l15] = f2bfb(acc[reg]);
    }
  }
}

// ---------------- final head -----------------------------------------------
__global__ __launch_bounds__(256) void final_kernel(
    const bf16* __restrict__ out1,
    const bf16* __restrict__ f1, const bf16* __restrict__ f2,
    const float* __restrict__ outW, const float* __restrict__ outb,
    float* __restrict__ dout) {
  const int wid = blockIdx.x * 4 + (threadIdx.x >> 6);
  const int lane = threadIdx.x & 63;
  const int b = wid / LQ, l = wid - b * LQ;
  const bf16* s1 = (l < WINQ) ? (out1 + ((size_t)b * LQ + l) * HQ)
                              : (f1 + ((size_t)b * MQ + (l - WINQ)) * HQ);
  int l2 = l + 10;  // D = 10
  if (l2 > LQ - 1) l2 = LQ - 1;
  const bf16* s2 = f2 + ((size_t)b * MQ + (l2 - WINQ)) * HQ;
  float s = 0.0f;
  #pragma unroll
  for (int jj = 0; jj < 4; ++jj) {
    int h = lane + jj * 64;
    s = fmaf(bf2f(s1[h]), outW[h], s);
    s = fmaf(bf2f(s2[h]), outW[HQ + h], s);
  }
  #pragma unroll
  for (int o = 32; o > 0; o >>= 1) s += __shfl_down(s, o);
  if (lane == 0) dout[wid] = sigmf(s + outb[0]);
}

extern "C" void kernel_launch(void* const* d_in, const int* in_sizes, int n_in,
                              void* d_out, int out_size, void* d_ws, size_t ws_size,
                              hipStream_t stream) {
  const float* x       = (const float*)d_in[0];
  const float* r1_Wih0 = (const float*)d_in[1];
  const float* r1_Whh0 = (const float*)d_in[2];
  const float* r1_bih0 = (const float*)d_in[3];
  const float* r1_bhh0 = (const float*)d_in[4];
  const float* r1_Wih1 = (const float*)d_in[5];
  const float* r1_Whh1 = (const float*)d_in[6];
  const float* r1_bih1 = (const float*)d_in[7];
  const float* r1_bhh1 = (const float*)d_in[8];
  const float* r2_Wih0 = (const float*)d_in[9];
  const float* r2_Whh0 = (const float*)d_in[10];
  const float* r2_bih0 = (const float*)d_in[11];
  const float* r2_bhh0 = (const float*)d_in[12];
  const float* r2_Wih1 = (const float*)d_in[13];
  const float* r2_Whh1 = (const float*)d_in[14];
  const float* r2_bih1 = (const float*)d_in[15];
  const float* r2_bhh1 = (const float*)d_in[16];
  const float* attn_w  = (const float*)d_in[17];
  const float* fc_W    = (const float*)d_in[18];
  const float* fc_b    = (const float*)d_in[19];
  const float* out_W   = (const float*)d_in[20];
  const float* out_b   = (const float*)d_in[21];

  char* p = (char*)d_ws;
  auto carve = [&](size_t bytes) {
    char* r = p;
    p += ((bytes + 255) / 256) * 256;
    return r;
  };
  const size_t WSZ = (size_t)GQ * HQ;            // 196608 (Whh/Wih1)
  const size_t XWR = (size_t)BQ * LQ * GQ;       // 39,321,600 per receiver
  const size_t SEQ = (size_t)BQ * LQ * HQ;       // 13,107,200
  const size_t FSEQ = (size_t)BQ * MQ * HQ;      // 12,451,840

  u16* whh0A = (u16*)carve(WSZ * 2);
  u16* whh0B = (u16*)carve(WSZ * 2);
  u16* whh1A = (u16*)carve(WSZ * 2);
  u16* whh1B = (u16*)carve(WSZ * 2);
  u16* wih1A = (u16*)carve(WSZ * 2);
  u16* wih1B = (u16*)carve(WSZ * 2);
  u16* fcwbf = (u16*)carve((size_t)HQ * 512 * 2);
  u16* xwbuf = (u16*)carve(XWR * 2 * 2);         // both receivers; reused L0 then L1
  u16* obuf  = (u16*)carve(SEQ * 2 * 2);         // L0 out; later overwritten by L1 out
  float* q1 = (float*)carve((size_t)BQ * LQ * 4);
  float* e1 = (float*)carve((size_t)BQ * LQ * 4);
  float* q2 = (float*)carve((size_t)BQ * LQ * 4);
  float* e2 = (float*)carve((size_t)BQ * LQ * 4);

  u16* xwA = xwbuf;
  u16* xwB = xwbuf + XWR;
  u16* oA  = obuf;                                // per-receiver sequence buffer
  u16* oB  = obuf + SEQ;
  // c/f alias the xw region (dead after layer-1 scan)
  u16* c1 = xwbuf;
  u16* c2 = c1 + FSEQ;
  u16* f1 = c2 + FSEQ;
  u16* f2 = f1 + FSEQ;

  // weight conversions (fp32 -> bf16)
  cvt_kernel<<<(WSZ / 4 + 255) / 256, 256, 0, stream>>>(r1_Whh0, whh0A, WSZ / 4);
  cvt_kernel<<<(WSZ / 4 + 255) / 256, 256, 0, stream>>>(r2_Whh0, whh0B, WSZ / 4);
  cvt_kernel<<<(WSZ / 4 + 255) / 256, 256, 0, stream>>>(r1_Whh1, whh1A, WSZ / 4);
  cvt_kernel<<<(WSZ / 4 + 255) / 256, 256, 0, stream>>>(r2_Whh1, whh1B, WSZ / 4);
  cvt_kernel<<<(WSZ / 4 + 255) / 256, 256, 0, stream>>>(r1_Wih1, wih1A, WSZ / 4);
  cvt_kernel<<<(WSZ / 4 + 255) / 256, 256, 0, stream>>>(r2_Wih1, wih1B, WSZ / 4);
  cvt_kernel<<<(HQ * 512 / 4 + 255) / 256, 256, 0, stream>>>(fc_W, fcwbf, HQ * 512 / 4);

  // layer 0
  xw0_kernel<<<dim3(BQ * LQ, 2), 256, 0, stream>>>(x, r1_Wih0, r1_bih0, r2_Wih0, r2_bih0, xwbuf);
  scan_mfma_kernel<<<dim3(BQ / 16, 2), 256, 0, stream>>>(
      xwA, xwB, whh0A, whh0B, r1_bhh0, r2_bhh0, oA, oB);
  // layer 1
  xw1_gemm_kernel<<<dim3(BQ * LQ / 64, 2), 256, 0, stream>>>(
      oA, oB, wih1A, wih1B, r1_bih1, r2_bih1, xwbuf);
  scan_mfma_kernel<<<dim3(BQ / 16, 2), 256, 0, stream>>>(
      xwA, xwB, whh1A, whh1B, r1_bhh1, r2_bhh1, oA, oB);

  // branch
  qe_kernel<<<(2 * BQ * LQ) / 4, 256, 0, stream>>>(
      (const bf16*)oA, (const bf16*)oB, attn_w, q1, e1, q2, e2);
  attnc_kernel<<<dim3(BQ, 2), 256, 0, stream>>>(
      (const bf16*)oA, (const bf16*)oB, q1, e1, q2, e2, (bf16*)c1, (bf16*)c2);
  fc_mfma_kernel<<<dim3((BQ * MQ) / 64, 2), 256, 0, stream>>>(
      c1, c2, oA, oB, fcwbf, fc_b, f1, f2);
  final_kernel<<<(BQ * LQ) / 4, 256, 0, stream>>>(
      (const bf16*)oA, (const bf16*)f1, (const bf16*)f2, out_W, out_b, (float*)d_out);
}

// Round 3
// 2007.339 us; speedup vs baseline: 3.9484x; 1.9407x over previous
//
#include <hip/hip_runtime.h>
#include <hip/hip_bf16.h>

#define BQ 512
#define LQ 100
#define HQ 256
#define GQ 768
#define WINQ 5
#define MQ 95    // L - WIN
#define HPAD 264 // h_lds row pad
#define XPAD 772 // xw_lds row pad (768+4): quads land on distinct bank groups

typedef __hip_bfloat16 bf16;
typedef unsigned short u16;
typedef __attribute__((ext_vector_type(8))) short short8;
typedef __attribute__((ext_vector_type(4))) float f32x4;

__device__ __forceinline__ float bf2f(bf16 v) { return __bfloat162float(v); }
__device__ __forceinline__ bf16 f2bf(float v) { return __float2bfloat16(v); }
__device__ __forceinline__ u16 f2bfb(float v) { return __builtin_bit_cast(u16, __float2bfloat16(v)); }
__device__ __forceinline__ float bfb2f(u16 u) {
  unsigned int x = ((unsigned int)u) << 16;
  return __builtin_bit_cast(float, x);
}
__device__ __forceinline__ float sigmf(float x) { return 1.0f / (1.0f + __expf(-x)); }
__device__ __forceinline__ float tanh_fast(float x) {
  float ax = fabsf(x);
  float e = __expf(-2.0f * ax);
  float t = (1.0f - e) / (1.0f + e);
  return copysignf(t, x);
}
__device__ __forceinline__ short8 ld8(const u16* p) { return *(const short8*)p; }
__device__ __forceinline__ short8 ld8nt(const u16* p) {
  return __builtin_nontemporal_load((const short8*)p);
}
__device__ __forceinline__ void st8nt(u16* p, short8 v) {
  __builtin_nontemporal_store(v, (short8*)p);
}
__device__ __forceinline__ f32x4 mfma16(short8 a, short8 b, f32x4 c) {
  return __builtin_amdgcn_mfma_f32_16x16x32_bf16(a, b, c, 0, 0, 0);
}

// ---------------- fp32 -> bf16 weight conversion ---------------------------
__global__ __launch_bounds__(256) void cvt_kernel(const float* __restrict__ src,
                                                  u16* __restrict__ dst, int n4) {
  int i = blockIdx.x * 256 + threadIdx.x;
  if (i < n4) {
    float4 v = reinterpret_cast<const float4*>(src)[i];
    ushort4 o;
    o.x = f2bfb(v.x); o.y = f2bfb(v.y); o.z = f2bfb(v.z); o.w = f2bfb(v.w);
    reinterpret_cast<ushort4*>(dst)[i] = o;
  }
}

// ---------------- xw0: x(B,L,3) @ Wih0^T + bih0 -> bf16 [row][768] ---------
__global__ __launch_bounds__(256) void xw0_kernel(
    const float* __restrict__ x,
    const float* __restrict__ WihA, const float* __restrict__ bihA,
    const float* __restrict__ WihB, const float* __restrict__ bihB,
    u16* __restrict__ xw) {
  const int row = blockIdx.x;            // b*L + t
  const int r = blockIdx.y;
  const float* Wih = r ? WihB : WihA;
  const float* bih = r ? bihB : bihA;
  u16* o = xw + (size_t)r * BQ * LQ * GQ + (size_t)row * GQ;
  const float x0 = x[(size_t)row * 3];
  const float x1 = x[(size_t)row * 3 + 1];
  const float x2 = x[(size_t)row * 3 + 2];
  for (int g = threadIdx.x; g < GQ; g += 256) {
    float v = fmaf(x0, Wih[g * 3], fmaf(x1, Wih[g * 3 + 1], fmaf(x2, Wih[g * 3 + 2], bih[g])));
    o[g] = f2bfb(v);
  }
}

// ---------------- xw1: o0(51200,256)bf16 @ Wih1^T + bih1 -> bf16 -----------
__global__ __launch_bounds__(256) void xw1_gemm_kernel(
    const u16* __restrict__ o0A, const u16* __restrict__ o0B,
    const u16* __restrict__ wihA, const u16* __restrict__ wihB,
    const float* __restrict__ bihA, const float* __restrict__ bihB,
    u16* __restrict__ xw) {
  const int r = blockIdx.y;
  const u16* A = r ? o0B : o0A;
  const u16* Wih = r ? wihB : wihA;
  const float* bih = r ? bihB : bihA;
  u16* out = xw + (size_t)r * BQ * LQ * GQ;
  const int row0 = blockIdx.x * 64;
  const int tid = threadIdx.x;
  const int w = tid >> 6, lane = tid & 63, l15 = lane & 15, quad = lane >> 4;

  __shared__ u16 a_lds[64][HPAD];
  for (int g = tid; g < 64 * 32; g += 256) {           // 16B groups
    int rr = g >> 5, c8 = (g & 31) * 8;
    *(short8*)&a_lds[rr][c8] = ld8(&A[(size_t)(row0 + rr) * HQ + c8]);
  }
  __syncthreads();

  for (int nt = 0; nt < 12; ++nt) {
    const int n0 = w * 192 + nt * 16;
    const u16* bp = Wih + (size_t)(n0 + l15) * HQ + quad * 8;
    short8 b[8];
    #pragma unroll
    for (int kt = 0; kt < 8; ++kt) b[kt] = ld8(bp + kt * 32);
    const float bias = bih[n0 + l15];
    #pragma unroll
    for (int mt = 0; mt < 4; ++mt) {
      f32x4 acc = {bias, bias, bias, bias};
      #pragma unroll
      for (int kt = 0; kt < 8; ++kt) {
        short8 a = ld8(&a_lds[mt * 16 + l15][kt * 32 + quad * 8]);
        acc = mfma16(a, b[kt], acc);
      }
      #pragma unroll
      for (int reg = 0; reg < 4; ++reg) {
        int row = row0 + mt * 16 + quad * 4 + reg;
        out[(size_t)row * GQ + n0 + l15] = f2bfb(acc[reg]);
      }
    }
  }
}

// ---------------- MFMA streaming GRU scan (register-pipelined) -------------
// 256 thr (4 waves), 16 batch rows/block. Wave w owns hidden cols [w*64,w*64+64).
// Whh B-frags: depth-6 register ring (L2-latency covering). xw: staged via LDS
// one step ahead with coalesced nontemporal 16B loads. out: written one step
// late via LDS readback as coalesced nontemporal 16B stores.
__global__ __launch_bounds__(256, 1) void scan_mfma_kernel(
    const u16* __restrict__ xwA, const u16* __restrict__ xwB,
    const u16* __restrict__ whhA, const u16* __restrict__ whhB,
    const float* __restrict__ bhhA, const float* __restrict__ bhhB,
    u16* __restrict__ outA, u16* __restrict__ outB) {
  const int r = blockIdx.y;
  const u16* xw = r ? xwB : xwA;
  const u16* whh = r ? whhB : whhA;
  const float* bhh = r ? bhhB : bhhA;
  u16* out = r ? outB : outA;
  const int b0 = blockIdx.x * 16;
  const int tid = threadIdx.x;
  const int w = tid >> 6, lane = tid & 63, l15 = lane & 15, quad = lane >> 4;
  const int jbase = w * 64;

  __shared__ u16 h_lds[2][16][HPAD];
  __shared__ u16 xwl[2][16][XPAD];

  for (int i = tid; i < 16 * HPAD; i += 256)
    h_lds[0][i / HPAD][i % HPAD] = 0;

  // xw staging geometry: 16 rows x 96 16B-chunks = 1536 chunks, 6 per thread
  int sm[6], sc8[6];
  #pragma unroll
  for (int k = 0; k < 6; ++k) {
    int idx = tid + k * 256;
    sm[k] = idx / 96;
    sc8[k] = (idx - sm[k] * 96) * 8;
  }
  // out readback geometry: 16 rows x 32 chunks = 512, 2 per thread
  const int om0 = tid >> 5, oc0 = (tid & 31) * 8;
  const int om1 = (tid + 256) >> 5, oc1 = oc0;

  // stage xw(0) -> xwl[0]
  #pragma unroll
  for (int k = 0; k < 6; ++k) {
    short8 v = ld8nt(&xw[((size_t)(b0 + sm[k]) * LQ + 0) * GQ + sc8[k]]);
    *(short8*)&xwl[0][sm[k]][sc8[k]] = v;
  }
  // prefetch xw(1) -> regs
  short8 xg[6];
  #pragma unroll
  for (int k = 0; k < 6; ++k)
    xg[k] = ld8nt(&xw[((size_t)(b0 + sm[k]) * LQ + (LQ > 1 ? 1 : 0)) * GQ + sc8[k]]);

  float bh[12];
  #pragma unroll
  for (int i = 0; i < 12; ++i)
    bh[i] = bhh[(i >> 2) * HQ + jbase + (i & 3) * 16 + l15];

  float hreg[4][4];
  #pragma unroll
  for (int jt = 0; jt < 4; ++jt)
    #pragma unroll
    for (int reg = 0; reg < 4; ++reg) hreg[jt][reg] = 0.0f;

  __syncthreads();

  for (int t = 0; t < LQ; ++t) {
    const int rb = t & 1, wb = rb ^ 1;

    // A fragments from LDS h(t)
    short8 a[8];
    #pragma unroll
    for (int kt = 0; kt < 8; ++kt)
      a[kt] = ld8(&h_lds[rb][l15][kt * 32 + quad * 8]);

    // out(t-1): coalesced readback + nontemporal wide stores
    if (t > 0) {
      short8 h0 = ld8(&h_lds[rb][om0][oc0]);
      short8 h1 = ld8(&h_lds[rb][om1][oc1]);
      st8nt(&out[((size_t)(b0 + om0) * LQ + (t - 1)) * HQ + oc0], h0);
      st8nt(&out[((size_t)(b0 + om1) * LQ + (t - 1)) * HQ + oc1], h1);
    }

    // commit xw(t+1) (prefetched last step) into LDS
    #pragma unroll
    for (int k = 0; k < 6; ++k)
      *(short8*)&xwl[wb][sm[k]][sc8[k]] = xg[k];

    // B-ring preload: tiles 0..5 (i = g*4+jt)
    short8 bb[6][8];
    #pragma unroll
    for (int i = 0; i < 6; ++i) {
      const u16* bp = whh + (size_t)((i >> 2) * HQ + jbase + (i & 3) * 16 + l15) * HQ + quad * 8;
      #pragma unroll
      for (int kt = 0; kt < 8; ++kt) bb[i][kt] = ld8(bp + kt * 32);
    }

    // prefetch xw(t+2) for next step
    {
      const int tn = (t + 2 < LQ) ? (t + 2) : (LQ - 1);
      #pragma unroll
      for (int k = 0; k < 6; ++k)
        xg[k] = ld8nt(&xw[((size_t)(b0 + sm[k]) * LQ + tn) * GQ + sc8[k]]);
    }

    f32x4 acc[12];
    #pragma unroll
    for (int i = 0; i < 12; ++i) acc[i] = f32x4{bh[i], bh[i], bh[i], bh[i]};

    // MFMA stream with ring reload (lookahead 5 tiles)
    #pragma unroll
    for (int i = 0; i < 12; ++i) {
      #pragma unroll
      for (int kt = 0; kt < 8; ++kt)
        acc[i] = mfma16(a[kt], bb[i % 6][kt], acc[i]);
      if (i + 6 < 12) {
        const int n = i + 6;
        const u16* bp = whh + (size_t)((n >> 2) * HQ + jbase + (n & 3) * 16 + l15) * HQ + quad * 8;
        #pragma unroll
        for (int kt = 0; kt < 8; ++kt) bb[i % 6][kt] = ld8(bp + kt * 32);
      }
    }

    // epilogue: gate math; xv from LDS; h carry fp32 in regs
    #pragma unroll
    for (int jt = 0; jt < 4; ++jt) {
      const int j = jbase + jt * 16 + l15;
      #pragma unroll
      for (int reg = 0; reg < 4; ++reg) {
        const int m = quad * 4 + reg;
        const float xr = bfb2f(xwl[rb][m][jbase + jt * 16 + l15]);
        const float xz = bfb2f(xwl[rb][m][HQ + jbase + jt * 16 + l15]);
        const float xn = bfb2f(xwl[rb][m][2 * HQ + jbase + jt * 16 + l15]);
        const float rg = sigmf(acc[jt][reg] + xr);
        const float zg = sigmf(acc[4 + jt][reg] + xz);
        const float ng = tanh_fast(fmaf(rg, acc[8 + jt][reg], xn));
        const float hn = fmaf(zg, hreg[jt][reg] - ng, ng);
        hreg[jt][reg] = hn;
        h_lds[wb][m][j] = f2bfb(hn);
      }
    }
    __syncthreads();
  }

  // final out(99): h written to h_lds[(99&1)^1] = h_lds[0]
  {
    short8 h0 = ld8(&h_lds[0][om0][oc0]);
    short8 h1 = ld8(&h_lds[0][om1][oc1]);
    st8nt(&out[((size_t)(b0 + om0) * LQ + (LQ - 1)) * HQ + oc0], h0);
    st8nt(&out[((size_t)(b0 + om1) * LQ + (LQ - 1)) * HQ + oc1], h1);
  }
}

// ------- fused attention: q/e dots + softmax + windowed context ------------
// one block per (b, branch); out[b] staged once in LDS (coalesced).
__global__ __launch_bounds__(256) void attn_fused_kernel(
    const u16* __restrict__ out1, const u16* __restrict__ out2,
    const float* __restrict__ attn_w,
    u16* __restrict__ c1, u16* __restrict__ c2) {
  const int b = blockIdx.x;
  const int br = blockIdx.y;
  const u16* out = br ? out2 : out1;
  u16* cb = br ? c2 : c1;
  const int tid = threadIdx.x;
  const int w = tid >> 6, lane = tid & 63;

  __shared__ u16 ol[LQ][HPAD];
  __shared__ float qv[LQ], ev[LQ];

  for (int idx = tid; idx < LQ * 32; idx += 256) {
    int row = idx >> 5, c8 = (idx & 31) * 8;
    *(short8*)&ol[row][c8] = ld8(&out[((size_t)b * LQ + row) * HQ + c8]);
  }
  __syncthreads();

  // q/e: wave w handles l = w, w+4, ...
  float aq[4], ae[4];
  #pragma unroll
  for (int jj = 0; jj < 4; ++jj) {
    aq[jj] = attn_w[lane + 64 * jj];
    ae[jj] = attn_w[HQ + lane + 64 * jj];
  }
  for (int l = w; l < LQ; l += 4) {
    float sq = 0.f, se = 0.f;
    #pragma unroll
    for (int jj = 0; jj < 4; ++jj) {
      float v = bfb2f(ol[l][lane + 64 * jj]);
      sq = fmaf(v, aq[jj], sq);
      se = fmaf(v, ae[jj], se);
    }
    #pragma unroll
    for (int o = 32; o > 0; o >>= 1) { sq += __shfl_down(sq, o); se += __shfl_down(se, o); }
    if (lane == 0) { qv[l] = sq; ev[l] = se; }
  }
  __syncthreads();

  // context: thread owns hidden col tid
  for (int m = 0; m < MQ; ++m) {
    const float qq = qv[m + WINQ];
    float s[WINQ];
    float mx = -1e30f;
    #pragma unroll
    for (int k = 0; k < WINQ; ++k) { s[k] = qq + ev[m + k]; mx = fmaxf(mx, s[k]); }
    float sum = 0.f;
    #pragma unroll
    for (int k = 0; k < WINQ; ++k) { s[k] = __expf(s[k] - mx); sum += s[k]; }
    const float inv = 1.0f / sum;
    float accv = 0.f;
    #pragma unroll
    for (int k = 0; k < WINQ; ++k)
      accv = fmaf(s[k], bfb2f(ol[m + k][tid]), accv);
    cb[((size_t)b * MQ + m) * HQ + tid] = f2bfb(accv * inv);
  }
}

// ---------------- fused FC via MFMA: [c | out] @ fcW^T + fcb ---------------
__global__ __launch_bounds__(256) void fc_mfma_kernel(
    const u16* __restrict__ c1, const u16* __restrict__ c2,
    const u16* __restrict__ o1, const u16* __restrict__ o2,
    const u16* __restrict__ fcw, const float* __restrict__ fcb,
    u16* __restrict__ f1, u16* __restrict__ f2) {
  const int br = blockIdx.y;
  const u16* cb = br ? c2 : c1;
  const u16* ob = br ? o2 : o1;
  u16* fo = br ? f2 : f1;
  const int i0 = blockIdx.x * 64;
  const int tid = threadIdx.x;
  const int w = tid >> 6, lane = tid & 63, l15 = lane & 15, quad = lane >> 4;

  __shared__ u16 a_lds[64][520];
  for (int g = tid; g < 64 * 64; g += 256) {        // 16B groups, K=512
    int rr = g >> 6, c8 = (g & 63) * 8;
    int gi = i0 + rr;
    int bb = gi / MQ, mm = gi - bb * MQ;
    const u16* src = (c8 < HQ) ? &cb[(size_t)gi * HQ + c8]
                               : &ob[((size_t)bb * LQ + mm + WINQ) * HQ + (c8 - HQ)];
    *(short8*)&a_lds[rr][c8] = ld8(src);
  }
  __syncthreads();

  for (int nt = 0; nt < 4; ++nt) {
    const int n0 = w * 64 + nt * 16;
    const u16* bp = fcw + (size_t)(n0 + l15) * 512 + quad * 8;
    short8 b[16];
    #pragma unroll
    for (int kt = 0; kt < 16; ++kt) b[kt] = ld8(bp + kt * 32);
    const float bias = fcb[n0 + l15];
    #pragma unroll
    for (int mt = 0; mt < 4; ++mt) {
      f32x4 acc = {bias, bias, bias, bias};
      #pragma unroll
      for (int kt = 0; kt < 16; ++kt) {
        short8 a = ld8(&a_lds[mt * 16 + l15][kt * 32 + quad * 8]);
        acc = mfma16(a, b[kt], acc);
      }
      #pragma unroll
      for (int reg = 0; reg < 4; ++reg)
        fo[(size_t)(i0 + mt * 16 + quad * 4 + reg) * HQ + n0 + l15] = f2bfb(acc[reg]);
    }
  }
}

// ---------------- final head -----------------------------------------------
__global__ __launch_bounds__(256) void final_kernel(
    const bf16* __restrict__ out1,
    const bf16* __restrict__ f1, const bf16* __restrict__ f2,
    const float* __restrict__ outW, const float* __restrict__ outb,
    float* __restrict__ dout) {
  const int wid = blockIdx.x * 4 + (threadIdx.x >> 6);
  const int lane = threadIdx.x & 63;
  const int b = wid / LQ, l = wid - b * LQ;
  const bf16* s1 = (l < WINQ) ? (out1 + ((size_t)b * LQ + l) * HQ)
                              : (f1 + ((size_t)b * MQ + (l - WINQ)) * HQ);
  int l2 = l + 10;  // D = 10
  if (l2 > LQ - 1) l2 = LQ - 1;
  const bf16* s2 = f2 + ((size_t)b * MQ + (l2 - WINQ)) * HQ;
  float s = 0.0f;
  #pragma unroll
  for (int jj = 0; jj < 4; ++jj) {
    int h = lane + jj * 64;
    s = fmaf(bf2f(s1[h]), outW[h], s);
    s = fmaf(bf2f(s2[h]), outW[HQ + h], s);
  }
  #pragma unroll
  for (int o = 32; o > 0; o >>= 1) s += __shfl_down(s, o);
  if (lane == 0) dout[wid] = sigmf(s + outb[0]);
}

extern "C" void kernel_launch(void* const* d_in, const int* in_sizes, int n_in,
                              void* d_out, int out_size, void* d_ws, size_t ws_size,
                              hipStream_t stream) {
  const float* x       = (const float*)d_in[0];
  const float* r1_Wih0 = (const float*)d_in[1];
  const float* r1_Whh0 = (const float*)d_in[2];
  const float* r1_bih0 = (const float*)d_in[3];
  const float* r1_bhh0 = (const float*)d_in[4];
  const float* r1_Wih1 = (const float*)d_in[5];
  const float* r1_Whh1 = (const float*)d_in[6];
  const float* r1_bih1 = (const float*)d_in[7];
  const float* r1_bhh1 = (const float*)d_in[8];
  const float* r2_Wih0 = (const float*)d_in[9];
  const float* r2_Whh0 = (const float*)d_in[10];
  const float* r2_bih0 = (const float*)d_in[11];
  const float* r2_bhh0 = (const float*)d_in[12];
  const float* r2_Wih1 = (const float*)d_in[13];
  const float* r2_Whh1 = (const float*)d_in[14];
  const float* r2_bih1 = (const float*)d_in[15];
  const float* r2_bhh1 = (const float*)d_in[16];
  const float* attn_w  = (const float*)d_in[17];
  const float* fc_W    = (const float*)d_in[18];
  const float* fc_b    = (const float*)d_in[19];
  const float* out_W   = (const float*)d_in[20];
  const float* out_b   = (const float*)d_in[21];

  char* p = (char*)d_ws;
  auto carve = [&](size_t bytes) {
    char* r = p;
    p += ((bytes + 255) / 256) * 256;
    return r;
  };
  const size_t WSZ = (size_t)GQ * HQ;            // 196608 (Whh/Wih1)
  const size_t XWR = (size_t)BQ * LQ * GQ;       // 39,321,600 per receiver
  const size_t SEQ = (size_t)BQ * LQ * HQ;       // 13,107,200
  const size_t FSEQ = (size_t)BQ * MQ * HQ;      // 12,451,840

  u16* whh0A = (u16*)carve(WSZ * 2);
  u16* whh0B = (u16*)carve(WSZ * 2);
  u16* whh1A = (u16*)carve(WSZ * 2);
  u16* whh1B = (u16*)carve(WSZ * 2);
  u16* wih1A = (u16*)carve(WSZ * 2);
  u16* wih1B = (u16*)carve(WSZ * 2);
  u16* fcwbf = (u16*)carve((size_t)HQ * 512 * 2);
  u16* xwbuf = (u16*)carve(XWR * 2 * 2);         // both receivers; reused L0 then L1
  u16* obuf  = (u16*)carve(SEQ * 2 * 2);         // L0 out; later overwritten by L1 out

  u16* xwA = xwbuf;
  u16* xwB = xwbuf + XWR;
  u16* oA  = obuf;
  u16* oB  = obuf + SEQ;
  // c/f alias the xw region (dead after layer-1 scan)
  u16* c1 = xwbuf;
  u16* c2 = c1 + FSEQ;
  u16* f1 = c2 + FSEQ;
  u16* f2 = f1 + FSEQ;

  // weight conversions (fp32 -> bf16)
  cvt_kernel<<<(WSZ / 4 + 255) / 256, 256, 0, stream>>>(r1_Whh0, whh0A, WSZ / 4);
  cvt_kernel<<<(WSZ / 4 + 255) / 256, 256, 0, stream>>>(r2_Whh0, whh0B, WSZ / 4);
  cvt_kernel<<<(WSZ / 4 + 255) / 256, 256, 0, stream>>>(r1_Whh1, whh1A, WSZ / 4);
  cvt_kernel<<<(WSZ / 4 + 255) / 256, 256, 0, stream>>>(r2_Whh1, whh1B, WSZ / 4);
  cvt_kernel<<<(WSZ / 4 + 255) / 256, 256, 0, stream>>>(r1_Wih1, wih1A, WSZ / 4);
  cvt_kernel<<<(WSZ / 4 + 255) / 256, 256, 0, stream>>>(r2_Wih1, wih1B, WSZ / 4);
  cvt_kernel<<<(HQ * 512 / 4 + 255) / 256, 256, 0, stream>>>(fc_W, fcwbf, HQ * 512 / 4);

  // layer 0
  xw0_kernel<<<dim3(BQ * LQ, 2), 256, 0, stream>>>(x, r1_Wih0, r1_bih0, r2_Wih0, r2_bih0, xwbuf);
  scan_mfma_kernel<<<dim3(BQ / 16, 2), 256, 0, stream>>>(
      xwA, xwB, whh0A, whh0B, r1_bhh0, r2_bhh0, oA, oB);
  // layer 1
  xw1_gemm_kernel<<<dim3(BQ * LQ / 64, 2), 256, 0, stream>>>(
      oA, oB, wih1A, wih1B, r1_bih1, r2_bih1, xwbuf);
  scan_mfma_kernel<<<dim3(BQ / 16, 2), 256, 0, stream>>>(
      xwA, xwB, whh1A, whh1B, r1_bhh1, r2_bhh1, oA, oB);

  // branch
  attn_fused_kernel<<<dim3(BQ, 2), 256, 0, stream>>>(oA, oB, attn_w, c1, c2);
  fc_mfma_kernel<<<dim3((BQ * MQ) / 64, 2), 256, 0, stream>>>(c1, c2, oA, oB, fcwbf, fc_b, f1, f2);
  final_kernel<<<(BQ * LQ) / 4, 256, 0, stream>>>(
      (const bf16*)oA, (const bf16*)f1, (const bf16*)f2, out_W, out_b, (float*)d_out);
}

// Round 4
// 1599.151 us; speedup vs baseline: 4.9563x; 1.2553x over previous
//
#include <hip/hip_runtime.h>
#include <hip/hip_bf16.h>

#define BQ 512
#define LQ 100
#define HQ 256
#define GQ 768
#define WINQ 5
#define MQ 95    // L - WIN
#define HPAD 264 // h_lds row pad
#define XPAD 772 // xw_lds row pad: 2*772%32=8 -> 4 quads hit 4 distinct bank groups

typedef __hip_bfloat16 bf16;
typedef unsigned short u16;
typedef __attribute__((ext_vector_type(8))) short short8;
typedef __attribute__((ext_vector_type(4))) float f32x4;

__device__ __forceinline__ float bf2f(bf16 v) { return __bfloat162float(v); }
__device__ __forceinline__ bf16 f2bf(float v) { return __float2bfloat16(v); }
__device__ __forceinline__ u16 f2bfb(float v) { return __builtin_bit_cast(u16, __float2bfloat16(v)); }
__device__ __forceinline__ float bfb2f(u16 u) {
  unsigned int x = ((unsigned int)u) << 16;
  return __builtin_bit_cast(float, x);
}
__device__ __forceinline__ float sigmf(float x) { return 1.0f / (1.0f + __expf(-x)); }
__device__ __forceinline__ float tanh_fast(float x) {
  float ax = fabsf(x);
  float e = __expf(-2.0f * ax);
  float t = (1.0f - e) / (1.0f + e);
  return copysignf(t, x);
}
__device__ __forceinline__ short8 ld8(const u16* p) { return *(const short8*)p; }
__device__ __forceinline__ short8 ld8nt(const u16* p) {
  return __builtin_nontemporal_load((const short8*)p);
}
__device__ __forceinline__ void st8nt(u16* p, short8 v) {
  __builtin_nontemporal_store(v, (short8*)p);
}
__device__ __forceinline__ f32x4 mfma16(short8 a, short8 b, f32x4 c) {
  return __builtin_amdgcn_mfma_f32_16x16x32_bf16(a, b, c, 0, 0, 0);
}

// ---------------- all fp32 -> bf16 weight conversions in one launch --------
__global__ __launch_bounds__(256) void cvt7_kernel(
    const float* __restrict__ s0, const float* __restrict__ s1,
    const float* __restrict__ s2, const float* __restrict__ s3,
    const float* __restrict__ s4, const float* __restrict__ s5,
    const float* __restrict__ s6,
    u16* __restrict__ d0, u16* __restrict__ d1, u16* __restrict__ d2,
    u16* __restrict__ d3, u16* __restrict__ d4, u16* __restrict__ d5,
    u16* __restrict__ d6) {
  const int seg = blockIdx.y;
  const float* s; u16* d; int n4;
  switch (seg) {
    case 0: s = s0; d = d0; n4 = GQ * HQ / 4; break;
    case 1: s = s1; d = d1; n4 = GQ * HQ / 4; break;
    case 2: s = s2; d = d2; n4 = GQ * HQ / 4; break;
    case 3: s = s3; d = d3; n4 = GQ * HQ / 4; break;
    case 4: s = s4; d = d4; n4 = GQ * HQ / 4; break;
    case 5: s = s5; d = d5; n4 = GQ * HQ / 4; break;
    default: s = s6; d = d6; n4 = HQ * 512 / 4; break;
  }
  int i = blockIdx.x * 256 + threadIdx.x;
  if (i < n4) {
    float4 v = reinterpret_cast<const float4*>(s)[i];
    ushort4 o;
    o.x = f2bfb(v.x); o.y = f2bfb(v.y); o.z = f2bfb(v.z); o.w = f2bfb(v.w);
    reinterpret_cast<ushort4*>(d)[i] = o;
  }
}

// ---------------- xw0: x(B,L,3) @ Wih0^T + bih0 -> bf16 [row][768] ---------
__global__ __launch_bounds__(256) void xw0_kernel(
    const float* __restrict__ x,
    const float* __restrict__ WihA, const float* __restrict__ bihA,
    const float* __restrict__ WihB, const float* __restrict__ bihB,
    u16* __restrict__ xw) {
  const int r = blockIdx.y;
  const float* Wih = r ? WihB : WihA;
  const float* bih = r ? bihB : bihA;
  const int row0 = blockIdx.x * 16;
  u16* o = xw + (size_t)r * BQ * LQ * GQ;
  const int g = threadIdx.x;

  __shared__ float xs[16][3];
  if (threadIdx.x < 48) {
    int m = threadIdx.x / 3, i = threadIdx.x - m * 3;
    xs[m][i] = x[(size_t)(row0 + m) * 3 + i];
  }
  float wv[3][3], bv[3];
  #pragma unroll
  for (int s = 0; s < 3; ++s) {
    int gg = g + s * 256;
    wv[s][0] = Wih[gg * 3]; wv[s][1] = Wih[gg * 3 + 1]; wv[s][2] = Wih[gg * 3 + 2];
    bv[s] = bih[gg];
  }
  __syncthreads();
  for (int m = 0; m < 16; ++m) {
    const float x0 = xs[m][0], x1 = xs[m][1], x2 = xs[m][2];
    u16* orow = o + (size_t)(row0 + m) * GQ;
    #pragma unroll
    for (int s = 0; s < 3; ++s)
      orow[s * 256 + g] = f2bfb(fmaf(x0, wv[s][0], fmaf(x1, wv[s][1], fmaf(x2, wv[s][2], bv[s]))));
  }
}

// ---------------- xw1: o0(51200,256)bf16 @ Wih1^T + bih1 -> bf16 -----------
__global__ __launch_bounds__(256) void xw1_gemm_kernel(
    const u16* __restrict__ o0A, const u16* __restrict__ o0B,
    const u16* __restrict__ wihA, const u16* __restrict__ wihB,
    const float* __restrict__ bihA, const float* __restrict__ bihB,
    u16* __restrict__ xw) {
  const int r = blockIdx.y;
  const u16* A = r ? o0B : o0A;
  const u16* Wih = r ? wihB : wihA;
  const float* bih = r ? bihB : bihA;
  u16* out = xw + (size_t)r * BQ * LQ * GQ;
  const int row0 = blockIdx.x * 64;
  const int tid = threadIdx.x;
  const int w = tid >> 6, lane = tid & 63, l15 = lane & 15, quad = lane >> 4;

  __shared__ u16 a_lds[64][HPAD];
  for (int g = tid; g < 64 * 32; g += 256) {           // 16B groups
    int rr = g >> 5, c8 = (g & 31) * 8;
    *(short8*)&a_lds[rr][c8] = ld8(&A[(size_t)(row0 + rr) * HQ + c8]);
  }
  __syncthreads();

  for (int nt = 0; nt < 12; ++nt) {
    const int n0 = w * 192 + nt * 16;
    const u16* bp = Wih + (size_t)(n0 + l15) * HQ + quad * 8;
    short8 b[8];
    #pragma unroll
    for (int kt = 0; kt < 8; ++kt) b[kt] = ld8(bp + kt * 32);
    const float bias = bih[n0 + l15];
    #pragma unroll
    for (int mt = 0; mt < 4; ++mt) {
      f32x4 acc = {bias, bias, bias, bias};
      #pragma unroll
      for (int kt = 0; kt < 8; ++kt) {
        short8 a = ld8(&a_lds[mt * 16 + l15][kt * 32 + quad * 8]);
        acc = mfma16(a, b[kt], acc);
      }
      #pragma unroll
      for (int reg = 0; reg < 4; ++reg) {
        int row = row0 + mt * 16 + quad * 4 + reg;
        out[(size_t)row * GQ + n0 + l15] = f2bfb(acc[reg]);
      }
    }
  }
}

// ---------------- MFMA GRU scan, register-resident Whh ---------------------
// 256 thr (4 waves), 16 batch rows/block. Wave w owns hidden cols [w*64,w*64+64).
// All 96 B-fragments (this wave's Whh slice, 98 KB) preloaded into the unified
// VGPR/AGPR file ONCE and reused across all 100 steps -> no per-step L2 weight
// stream. Only 3 accs live at a time (per-jt processing) to fit 512 regs.
__global__ __launch_bounds__(256, 1) void scan_mfma_kernel(
    const u16* __restrict__ xwA, const u16* __restrict__ xwB,
    const u16* __restrict__ whhA, const u16* __restrict__ whhB,
    const float* __restrict__ bhhA, const float* __restrict__ bhhB,
    u16* __restrict__ outA, u16* __restrict__ outB) {
  const int r = blockIdx.y;
  const u16* xw = r ? xwB : xwA;
  const u16* whh = r ? whhB : whhA;
  const float* bhh = r ? bhhB : bhhA;
  u16* out = r ? outB : outA;
  const int b0 = blockIdx.x * 16;
  const int tid = threadIdx.x;
  const int w = tid >> 6, lane = tid & 63, l15 = lane & 15, quad = lane >> 4;
  const int jbase = w * 64;

  __shared__ u16 h_lds[2][16][HPAD];
  __shared__ u16 xwl[2][16][XPAD];

  for (int i = tid; i < 16 * HPAD; i += 256)
    h_lds[0][i / HPAD][i % HPAD] = 0;

  // resident B fragments: tile i = g*4+jt (n = g*256 + jbase + jt*16 + l15)
  short8 bb[12][8];
  #pragma unroll
  for (int i = 0; i < 12; ++i) {
    const u16* bp = whh + (size_t)((i >> 2) * HQ + jbase + (i & 3) * 16 + l15) * HQ + quad * 8;
    #pragma unroll
    for (int kt = 0; kt < 8; ++kt) bb[i][kt] = ld8(bp + kt * 32);
  }

  float bh[12];
  #pragma unroll
  for (int i = 0; i < 12; ++i)
    bh[i] = bhh[(i >> 2) * HQ + jbase + (i & 3) * 16 + l15];

  // xw staging geometry: 16 rows x 96 chunks, 6 chunks/thread
  int sm[6], sc8[6];
  #pragma unroll
  for (int k = 0; k < 6; ++k) {
    int idx = tid + k * 256;
    sm[k] = idx / 96;
    sc8[k] = (idx - sm[k] * 96) * 8;
  }
  // out readback geometry: 2 chunks/thread
  const int om0 = tid >> 5, oc0 = (tid & 31) * 8;
  const int om1 = om0 + 8;

  // stage xw(0); prefetch xw(1)
  #pragma unroll
  for (int k = 0; k < 6; ++k) {
    short8 v = ld8nt(&xw[(size_t)(b0 + sm[k]) * LQ * GQ + sc8[k]]);
    *(short8*)&xwl[0][sm[k]][sc8[k]] = v;
  }
  short8 xg[6];
  #pragma unroll
  for (int k = 0; k < 6; ++k)
    xg[k] = ld8nt(&xw[((size_t)(b0 + sm[k]) * LQ + 1) * GQ + sc8[k]]);

  __syncthreads();

  for (int t = 0; t < LQ; ++t) {
    const int rb = t & 1, wb = rb ^ 1;

    // A fragments from LDS h(t)
    short8 a[8];
    #pragma unroll
    for (int kt = 0; kt < 8; ++kt)
      a[kt] = ld8(&h_lds[rb][l15][kt * 32 + quad * 8]);

    // out(t-1) = h(t): coalesced readback + nontemporal wide stores
    if (t > 0) {
      short8 h0 = ld8(&h_lds[rb][om0][oc0]);
      short8 h1 = ld8(&h_lds[rb][om1][oc0]);
      st8nt(&out[((size_t)(b0 + om0) * LQ + (t - 1)) * HQ + oc0], h0);
      st8nt(&out[((size_t)(b0 + om1) * LQ + (t - 1)) * HQ + oc0], h1);
    }

    // commit xw(t+1) into LDS; prefetch xw(t+2)
    #pragma unroll
    for (int k = 0; k < 6; ++k)
      *(short8*)&xwl[wb][sm[k]][sc8[k]] = xg[k];
    {
      const int tn = (t + 2 < LQ) ? (t + 2) : (LQ - 1);
      #pragma unroll
      for (int k = 0; k < 6; ++k)
        xg[k] = ld8nt(&xw[((size_t)(b0 + sm[k]) * LQ + tn) * GQ + sc8[k]]);
    }

    // gates + epilogue, one 16-col slice (jt) at a time: only 3 accs live
    #pragma unroll
    for (int jt = 0; jt < 4; ++jt) {
      f32x4 accr = {bh[jt], bh[jt], bh[jt], bh[jt]};
      f32x4 accz = {bh[4 + jt], bh[4 + jt], bh[4 + jt], bh[4 + jt]};
      f32x4 accn = {bh[8 + jt], bh[8 + jt], bh[8 + jt], bh[8 + jt]};
      #pragma unroll
      for (int kt = 0; kt < 8; ++kt) {
        accr = mfma16(a[kt], bb[jt][kt], accr);
        accz = mfma16(a[kt], bb[4 + jt][kt], accz);
        accn = mfma16(a[kt], bb[8 + jt][kt], accn);
      }
      const int j = jbase + jt * 16 + l15;
      #pragma unroll
      for (int reg = 0; reg < 4; ++reg) {
        const int m = quad * 4 + reg;
        const float xr = bfb2f(xwl[rb][m][j]);
        const float xz = bfb2f(xwl[rb][m][HQ + j]);
        const float xn = bfb2f(xwl[rb][m][2 * HQ + j]);
        const float hold = bfb2f(h_lds[rb][m][j]);
        const float rg = sigmf(accr[reg] + xr);
        const float zg = sigmf(accz[reg] + xz);
        const float ng = tanh_fast(fmaf(rg, accn[reg], xn));
        const float hn = fmaf(zg, hold - ng, ng);
        h_lds[wb][m][j] = f2bfb(hn);
      }
    }
    __syncthreads();
  }

  // final out(99): state in h_lds[(99&1)^1] = h_lds[0]
  {
    short8 h0 = ld8(&h_lds[0][om0][oc0]);
    short8 h1 = ld8(&h_lds[0][om1][oc0]);
    st8nt(&out[((size_t)(b0 + om0) * LQ + (LQ - 1)) * HQ + oc0], h0);
    st8nt(&out[((size_t)(b0 + om1) * LQ + (LQ - 1)) * HQ + oc0], h1);
  }
}

// ------- fused attention: q/e dots + softmax + windowed context ------------
__global__ __launch_bounds__(256) void attn_fused_kernel(
    const u16* __restrict__ out1, const u16* __restrict__ out2,
    const float* __restrict__ attn_w,
    u16* __restrict__ c1, u16* __restrict__ c2) {
  const int b = blockIdx.x;
  const int br = blockIdx.y;
  const u16* out = br ? out2 : out1;
  u16* cb = br ? c2 : c1;
  const int tid = threadIdx.x;
  const int w = tid >> 6, lane = tid & 63;

  __shared__ u16 ol[LQ][HPAD];
  __shared__ float qv[LQ], ev[LQ];

  for (int idx = tid; idx < LQ * 32; idx += 256) {
    int row = idx >> 5, c8 = (idx & 31) * 8;
    *(short8*)&ol[row][c8] = ld8(&out[((size_t)b * LQ + row) * HQ + c8]);
  }
  __syncthreads();

  float aq[4], ae[4];
  #pragma unroll
  for (int jj = 0; jj < 4; ++jj) {
    aq[jj] = attn_w[lane + 64 * jj];
    ae[jj] = attn_w[HQ + lane + 64 * jj];
  }
  for (int l = w; l < LQ; l += 4) {
    float sq = 0.f, se = 0.f;
    #pragma unroll
    for (int jj = 0; jj < 4; ++jj) {
      float v = bfb2f(ol[l][lane + 64 * jj]);
      sq = fmaf(v, aq[jj], sq);
      se = fmaf(v, ae[jj], se);
    }
    #pragma unroll
    for (int o = 32; o > 0; o >>= 1) { sq += __shfl_down(sq, o); se += __shfl_down(se, o); }
    if (lane == 0) { qv[l] = sq; ev[l] = se; }
  }
  __syncthreads();

  for (int m = 0; m < MQ; ++m) {
    const float qq = qv[m + WINQ];
    float s[WINQ];
    float mx = -1e30f;
    #pragma unroll
    for (int k = 0; k < WINQ; ++k) { s[k] = qq + ev[m + k]; mx = fmaxf(mx, s[k]); }
    float sum = 0.f;
    #pragma unroll
    for (int k = 0; k < WINQ; ++k) { s[k] = __expf(s[k] - mx); sum += s[k]; }
    const float inv = 1.0f / sum;
    float accv = 0.f;
    #pragma unroll
    for (int k = 0; k < WINQ; ++k)
      accv = fmaf(s[k], bfb2f(ol[m + k][tid]), accv);
    cb[((size_t)b * MQ + m) * HQ + tid] = f2bfb(accv * inv);
  }
}

// ---------------- fused FC via MFMA: [c | out] @ fcW^T + fcb ---------------
__global__ __launch_bounds__(256) void fc_mfma_kernel(
    const u16* __restrict__ c1, const u16* __restrict__ c2,
    const u16* __restrict__ o1, const u16* __restrict__ o2,
    const u16* __restrict__ fcw, const float* __restrict__ fcb,
    u16* __restrict__ f1, u16* __restrict__ f2) {
  const int br = blockIdx.y;
  const u16* cb = br ? c2 : c1;
  const u16* ob = br ? o2 : o1;
  u16* fo = br ? f2 : f1;
  const int i0 = blockIdx.x * 64;
  const int tid = threadIdx.x;
  const int w = tid >> 6, lane = tid & 63, l15 = lane & 15, quad = lane >> 4;

  __shared__ u16 a_lds[64][520];
  for (int g = tid; g < 64 * 64; g += 256) {        // 16B groups, K=512
    int rr = g >> 6, c8 = (g & 63) * 8;
    int gi = i0 + rr;
    int bb = gi / MQ, mm = gi - bb * MQ;
    const u16* src = (c8 < HQ) ? &cb[(size_t)gi * HQ + c8]
                               : &ob[((size_t)bb * LQ + mm + WINQ) * HQ + (c8 - HQ)];
    *(short8*)&a_lds[rr][c8] = ld8(src);
  }
  __syncthreads();

  for (int nt = 0; nt < 4; ++nt) {
    const int n0 = w * 64 + nt * 16;
    const u16* bp = fcw + (size_t)(n0 + l15) * 512 + quad * 8;
    short8 b[16];
    #pragma unroll
    for (int kt = 0; kt < 16; ++kt) b[kt] = ld8(bp + kt * 32);
    const float bias = fcb[n0 + l15];
    #pragma unroll
    for (int mt = 0; mt < 4; ++mt) {
      f32x4 acc = {bias, bias, bias, bias};
      #pragma unroll
      for (int kt = 0; kt < 16; ++kt) {
        short8 a = ld8(&a_lds[mt * 16 + l15][kt * 32 + quad * 8]);
        acc = mfma16(a, b[kt], acc);
      }
      #pragma unroll
      for (int reg = 0; reg < 4; ++reg)
        fo[(size_t)(i0 + mt * 16 + quad * 4 + reg) * HQ + n0 + l15] = f2bfb(acc[reg]);
    }
  }
}

// ---------------- final head -----------------------------------------------
__global__ __launch_bounds__(256) void final_kernel(
    const bf16* __restrict__ out1,
    const bf16* __restrict__ f1, const bf16* __restrict__ f2,
    const float* __restrict__ outW, const float* __restrict__ outb,
    float* __restrict__ dout) {
  const int wid = blockIdx.x * 4 + (threadIdx.x >> 6);
  const int lane = threadIdx.x & 63;
  const int b = wid / LQ, l = wid - b * LQ;
  const bf16* s1 = (l < WINQ) ? (out1 + ((size_t)b * LQ + l) * HQ)
                              : (f1 + ((size_t)b * MQ + (l - WINQ)) * HQ);
  int l2 = l + 10;  // D = 10
  if (l2 > LQ - 1) l2 = LQ - 1;
  const bf16* s2 = f2 + ((size_t)b * MQ + (l2 - WINQ)) * HQ;
  float s = 0.0f;
  #pragma unroll
  for (int jj = 0; jj < 4; ++jj) {
    int h = lane + jj * 64;
    s = fmaf(bf2f(s1[h]), outW[h], s);
    s = fmaf(bf2f(s2[h]), outW[HQ + h], s);
  }
  #pragma unroll
  for (int o = 32; o > 0; o >>= 1) s += __shfl_down(s, o);
  if (lane == 0) dout[wid] = sigmf(s + outb[0]);
}

extern "C" void kernel_launch(void* const* d_in, const int* in_sizes, int n_in,
                              void* d_out, int out_size, void* d_ws, size_t ws_size,
                              hipStream_t stream) {
  const float* x       = (const float*)d_in[0];
  const float* r1_Wih0 = (const float*)d_in[1];
  const float* r1_Whh0 = (const float*)d_in[2];
  const float* r1_bih0 = (const float*)d_in[3];
  const float* r1_bhh0 = (const float*)d_in[4];
  const float* r1_Wih1 = (const float*)d_in[5];
  const float* r1_Whh1 = (const float*)d_in[6];
  const float* r1_bih1 = (const float*)d_in[7];
  const float* r1_bhh1 = (const float*)d_in[8];
  const float* r2_Wih0 = (const float*)d_in[9];
  const float* r2_Whh0 = (const float*)d_in[10];
  const float* r2_bih0 = (const float*)d_in[11];
  const float* r2_bhh0 = (const float*)d_in[12];
  const float* r2_Wih1 = (const float*)d_in[13];
  const float* r2_Whh1 = (const float*)d_in[14];
  const float* r2_bih1 = (const float*)d_in[15];
  const float* r2_bhh1 = (const float*)d_in[16];
  const float* attn_w  = (const float*)d_in[17];
  const float* fc_W    = (const float*)d_in[18];
  const float* fc_b    = (const float*)d_in[19];
  const float* out_W   = (const float*)d_in[20];
  const float* out_b   = (const float*)d_in[21];

  char* p = (char*)d_ws;
  auto carve = [&](size_t bytes) {
    char* r = p;
    p += ((bytes + 255) / 256) * 256;
    return r;
  };
  const size_t WSZ = (size_t)GQ * HQ;            // 196608 (Whh/Wih1)
  const size_t XWR = (size_t)BQ * LQ * GQ;       // 39,321,600 per receiver
  const size_t SEQ = (size_t)BQ * LQ * HQ;       // 13,107,200
  const size_t FSEQ = (size_t)BQ * MQ * HQ;      // 12,451,840

  u16* whh0A = (u16*)carve(WSZ * 2);
  u16* whh0B = (u16*)carve(WSZ * 2);
  u16* whh1A = (u16*)carve(WSZ * 2);
  u16* whh1B = (u16*)carve(WSZ * 2);
  u16* wih1A = (u16*)carve(WSZ * 2);
  u16* wih1B = (u16*)carve(WSZ * 2);
  u16* fcwbf = (u16*)carve((size_t)HQ * 512 * 2);
  u16* xwbuf = (u16*)carve(XWR * 2 * 2);         // both receivers; reused L0 then L1
  u16* obuf  = (u16*)carve(SEQ * 2 * 2);         // L0 out; later overwritten by L1 out

  u16* xwA = xwbuf;
  u16* xwB = xwbuf + XWR;
  u16* oA  = obuf;
  u16* oB  = obuf + SEQ;
  // c/f alias the xw region (dead after layer-1 scan)
  u16* c1 = xwbuf;
  u16* c2 = c1 + FSEQ;
  u16* f1 = c2 + FSEQ;
  u16* f2 = f1 + FSEQ;

  // all weight conversions, one launch
  cvt7_kernel<<<dim3((WSZ / 4 + 255) / 256, 7), 256, 0, stream>>>(
      r1_Whh0, r2_Whh0, r1_Whh1, r2_Whh1, r1_Wih1, r2_Wih1, fc_W,
      whh0A, whh0B, whh1A, whh1B, wih1A, wih1B, fcwbf);

  // layer 0
  xw0_kernel<<<dim3(BQ * LQ / 16, 2), 256, 0, stream>>>(
      x, r1_Wih0, r1_bih0, r2_Wih0, r2_bih0, xwbuf);
  scan_mfma_kernel<<<dim3(BQ / 16, 2), 256, 0, stream>>>(
      xwA, xwB, whh0A, whh0B, r1_bhh0, r2_bhh0, oA, oB);
  // layer 1
  xw1_gemm_kernel<<<dim3(BQ * LQ / 64, 2), 256, 0, stream>>>(
      oA, oB, wih1A, wih1B, r1_bih1, r2_bih1, xwbuf);
  scan_mfma_kernel<<<dim3(BQ / 16, 2), 256, 0, stream>>>(
      xwA, xwB, whh1A, whh1B, r1_bhh1, r2_bhh1, oA, oB);

  // branch
  attn_fused_kernel<<<dim3(BQ, 2), 256, 0, stream>>>(oA, oB, attn_w, c1, c2);
  fc_mfma_kernel<<<dim3((BQ * MQ) / 64, 2), 256, 0, stream>>>(c1, c2, oA, oB, fcwbf, fc_b, f1, f2);
  final_kernel<<<(BQ * LQ) / 4, 256, 0, stream>>>(
      (const bf16*)oA, (const bf16*)f1, (const bf16*)f2, out_W, out_b, (float*)d_out);
}

// Round 5
// 1108.713 us; speedup vs baseline: 7.1486x; 1.4423x over previous
//
#include <hip/hip_runtime.h>
#include <hip/hip_bf16.h>

#define BQ 512
#define LQ 100
#define HQ 256
#define GQ 768
#define WINQ 5
#define MQ 95    // L - WIN
#define HPAD 264 // h_lds row pad

typedef __hip_bfloat16 bf16;
typedef unsigned short u16;
typedef __attribute__((ext_vector_type(8))) short short8;
typedef __attribute__((ext_vector_type(4))) float f32x4;

__device__ __forceinline__ float bf2f(bf16 v) { return __bfloat162float(v); }
__device__ __forceinline__ bf16 f2bf(float v) { return __float2bfloat16(v); }
__device__ __forceinline__ u16 f2bfb(float v) { return __builtin_bit_cast(u16, __float2bfloat16(v)); }
__device__ __forceinline__ float bfb2f(u16 u) {
  unsigned int x = ((unsigned int)u) << 16;
  return __builtin_bit_cast(float, x);
}
__device__ __forceinline__ float rcpf(float x) { return __builtin_amdgcn_rcpf(x); }
__device__ __forceinline__ float sigmf(float x) { return rcpf(1.0f + __expf(-x)); }
__device__ __forceinline__ float tanh_fast(float x) {
  float ax = fabsf(x);
  float e = __expf(-2.0f * ax);
  float t = (1.0f - e) * rcpf(1.0f + e);
  return copysignf(t, x);
}
__device__ __forceinline__ short8 ld8(const u16* p) { return *(const short8*)p; }
__device__ __forceinline__ void st8nt(u16* p, short8 v) {
  __builtin_nontemporal_store(v, (short8*)p);
}
__device__ __forceinline__ f32x4 mfma16(short8 a, short8 b, f32x4 c) {
  return __builtin_amdgcn_mfma_f32_16x16x32_bf16(a, b, c, 0, 0, 0);
}
// async global->LDS, 16B per lane; LDS dest = wave-uniform base + lane*16
__device__ __forceinline__ void gl_lds16(const u16* g, u16* l) {
  __builtin_amdgcn_global_load_lds(
      (const __attribute__((address_space(1))) unsigned int*)g,
      (__attribute__((address_space(3))) unsigned int*)l, 16, 0, 0);
}

// ---------------- all fp32 -> bf16 weight conversions in one launch --------
__global__ __launch_bounds__(256) void cvt7_kernel(
    const float* __restrict__ s0, const float* __restrict__ s1,
    const float* __restrict__ s2, const float* __restrict__ s3,
    const float* __restrict__ s4, const float* __restrict__ s5,
    const float* __restrict__ s6,
    u16* __restrict__ d0, u16* __restrict__ d1, u16* __restrict__ d2,
    u16* __restrict__ d3, u16* __restrict__ d4, u16* __restrict__ d5,
    u16* __restrict__ d6) {
  const int seg = blockIdx.y;
  const float* s; u16* d; int n4;
  switch (seg) {
    case 0: s = s0; d = d0; n4 = GQ * HQ / 4; break;
    case 1: s = s1; d = d1; n4 = GQ * HQ / 4; break;
    case 2: s = s2; d = d2; n4 = GQ * HQ / 4; break;
    case 3: s = s3; d = d3; n4 = GQ * HQ / 4; break;
    case 4: s = s4; d = d4; n4 = GQ * HQ / 4; break;
    case 5: s = s5; d = d5; n4 = GQ * HQ / 4; break;
    default: s = s6; d = d6; n4 = HQ * 512 / 4; break;
  }
  int i = blockIdx.x * 256 + threadIdx.x;
  if (i < n4) {
    float4 v = reinterpret_cast<const float4*>(s)[i];
    ushort4 o;
    o.x = f2bfb(v.x); o.y = f2bfb(v.y); o.z = f2bfb(v.z); o.w = f2bfb(v.w);
    reinterpret_cast<ushort4*>(d)[i] = o;
  }
}

// ---------------- xw0: x(B,L,3) @ Wih0^T + bih0 -> bf16 [row][768] ---------
__global__ __launch_bounds__(256) void xw0_kernel(
    const float* __restrict__ x,
    const float* __restrict__ WihA, const float* __restrict__ bihA,
    const float* __restrict__ WihB, const float* __restrict__ bihB,
    u16* __restrict__ xw) {
  const int r = blockIdx.y;
  const float* Wih = r ? WihB : WihA;
  const float* bih = r ? bihB : bihA;
  const int row0 = blockIdx.x * 16;
  u16* o = xw + (size_t)r * BQ * LQ * GQ;
  const int g = threadIdx.x;

  __shared__ float xs[16][3];
  if (threadIdx.x < 48) {
    int m = threadIdx.x / 3, i = threadIdx.x - m * 3;
    xs[m][i] = x[(size_t)(row0 + m) * 3 + i];
  }
  float wv[3][3], bv[3];
  #pragma unroll
  for (int s = 0; s < 3; ++s) {
    int gg = g + s * 256;
    wv[s][0] = Wih[gg * 3]; wv[s][1] = Wih[gg * 3 + 1]; wv[s][2] = Wih[gg * 3 + 2];
    bv[s] = bih[gg];
  }
  __syncthreads();
  for (int m = 0; m < 16; ++m) {
    const float x0 = xs[m][0], x1 = xs[m][1], x2 = xs[m][2];
    u16* orow = o + (size_t)(row0 + m) * GQ;
    #pragma unroll
    for (int s = 0; s < 3; ++s)
      orow[s * 256 + g] = f2bfb(fmaf(x0, wv[s][0], fmaf(x1, wv[s][1], fmaf(x2, wv[s][2], bv[s]))));
  }
}

// ---------------- xw1: o0(51200,256)bf16 @ Wih1^T + bih1 -> bf16 -----------
__global__ __launch_bounds__(256) void xw1_gemm_kernel(
    const u16* __restrict__ o0A, const u16* __restrict__ o0B,
    const u16* __restrict__ wihA, const u16* __restrict__ wihB,
    const float* __restrict__ bihA, const float* __restrict__ bihB,
    u16* __restrict__ xw) {
  const int r = blockIdx.y;
  const u16* A = r ? o0B : o0A;
  const u16* Wih = r ? wihB : wihA;
  const float* bih = r ? bihB : bihA;
  u16* out = xw + (size_t)r * BQ * LQ * GQ;
  const int row0 = blockIdx.x * 64;
  const int tid = threadIdx.x;
  const int w = tid >> 6, lane = tid & 63, l15 = lane & 15, quad = lane >> 4;

  __shared__ u16 a_lds[64][HPAD];
  for (int g = tid; g < 64 * 32; g += 256) {           // 16B groups
    int rr = g >> 5, c8 = (g & 31) * 8;
    *(short8*)&a_lds[rr][c8] = ld8(&A[(size_t)(row0 + rr) * HQ + c8]);
  }
  __syncthreads();

  for (int nt = 0; nt < 12; ++nt) {
    const int n0 = w * 192 + nt * 16;
    const u16* bp = Wih + (size_t)(n0 + l15) * HQ + quad * 8;
    short8 b[8];
    #pragma unroll
    for (int kt = 0; kt < 8; ++kt) b[kt] = ld8(bp + kt * 32);
    const float bias = bih[n0 + l15];
    #pragma unroll
    for (int mt = 0; mt < 4; ++mt) {
      f32x4 acc = {bias, bias, bias, bias};
      #pragma unroll
      for (int kt = 0; kt < 8; ++kt) {
        short8 a = ld8(&a_lds[mt * 16 + l15][kt * 32 + quad * 8]);
        acc = mfma16(a, b[kt], acc);
      }
      #pragma unroll
      for (int reg = 0; reg < 4; ++reg) {
        int row = row0 + mt * 16 + quad * 4 + reg;
        out[(size_t)row * GQ + n0 + l15] = f2bfb(acc[reg]);
      }
    }
  }
}

// ---------------- MFMA GRU scan: 8 waves, register-resident Whh ------------
// 512 thr (8 waves), 16 batch rows/block. Wave w owns hidden cols
// [w*32, w*32+32): bb[6][8]=192 regs fits the 256-reg/wave budget at
// 2 waves/SIMD, so Whh is truly register-resident across all 100 steps.
// xw staged via async global_load_lds (no data regs); h via LDS dbuf.
__global__ __launch_bounds__(512, 2) void scan_mfma_kernel(
    const u16* __restrict__ xwA, const u16* __restrict__ xwB,
    const u16* __restrict__ whhA, const u16* __restrict__ whhB,
    const float* __restrict__ bhhA, const float* __restrict__ bhhB,
    u16* __restrict__ outA, u16* __restrict__ outB) {
  const int r = blockIdx.y;
  const u16* xw = r ? xwB : xwA;
  const u16* whh = r ? whhB : whhA;
  const float* bhh = r ? bhhB : bhhA;
  u16* out = r ? outB : outA;
  const int b0 = blockIdx.x * 16;
  const int tid = threadIdx.x;
  const int w = tid >> 6, lane = tid & 63, l15 = lane & 15, quad = lane >> 4;
  const int jbase = w * 32;

  __shared__ u16 h_lds[2][16][HPAD];
  __shared__ u16 xwl[2][16 * GQ];   // unpadded: chunk-contiguous for global_load_lds

  for (int i = tid; i < 16 * HPAD; i += 512)
    h_lds[0][i / HPAD][i % HPAD] = 0;

  // resident Whh slice: tile i = g*2+jt, n = g*256 + jbase + jt*16 + l15
  short8 bb[6][8];
  #pragma unroll
  for (int i = 0; i < 6; ++i) {
    const u16* bp = whh + (size_t)((i >> 1) * HQ + jbase + (i & 1) * 16 + l15) * HQ + quad * 8;
    #pragma unroll
    for (int kt = 0; kt < 8; ++kt) bb[i][kt] = ld8(bp + kt * 32);
  }
  float bh[6];
  #pragma unroll
  for (int i = 0; i < 6; ++i)
    bh[i] = bhh[(i >> 1) * HQ + jbase + (i & 1) * 16 + l15];

  // xw staging: 1536 16B-chunks/step; wave w covers [w*192, w*192+192), 3 calls
  const u16* gsrc[3];
  int ldsoff[3];
  #pragma unroll
  for (int k = 0; k < 3; ++k) {
    int c = w * 192 + k * 64 + lane;
    int m = c / 96, ch = c - m * 96;
    gsrc[k] = xw + (size_t)(b0 + m) * LQ * GQ + ch * 8;
    ldsoff[k] = (w * 192 + k * 64) * 8;   // u16 units; +lane*16B by HW
  }
  // out readback: 1 chunk/thread (16 rows x 32 chunks)
  const int om = tid >> 5, oc = (tid & 31) * 8;

  // stage xw(0) into xwl[0]
  #pragma unroll
  for (int k = 0; k < 3; ++k) gl_lds16(gsrc[k], &xwl[0][ldsoff[k]]);

  __syncthreads();

  for (int t = 0; t < LQ; ++t) {
    const int rb = t & 1, wb = rb ^ 1;

    // async prefetch xw(t+1) -> xwl[wb]; drained by barrier at loop end
    const int tn = (t + 1 < LQ) ? t + 1 : t;
    #pragma unroll
    for (int k = 0; k < 3; ++k)
      gl_lds16(gsrc[k] + (size_t)tn * GQ, &xwl[wb][ldsoff[k]]);

    // A fragments from LDS h(t)
    short8 a[8];
    #pragma unroll
    for (int kt = 0; kt < 8; ++kt)
      a[kt] = ld8(&h_lds[rb][l15][kt * 32 + quad * 8]);

    // out(t-1) = h_lds[rb]: coalesced readback + nontemporal store
    if (t > 0) {
      short8 h0 = ld8(&h_lds[rb][om][oc]);
      st8nt(&out[((size_t)(b0 + om) * LQ + (t - 1)) * HQ + oc], h0);
    }

    // 2 j-slices; 3 gate accs live at a time
    #pragma unroll
    for (int jt = 0; jt < 2; ++jt) {
      f32x4 accr = {bh[jt], bh[jt], bh[jt], bh[jt]};
      f32x4 accz = {bh[2 + jt], bh[2 + jt], bh[2 + jt], bh[2 + jt]};
      f32x4 accn = {bh[4 + jt], bh[4 + jt], bh[4 + jt], bh[4 + jt]};
      #pragma unroll
      for (int kt = 0; kt < 8; ++kt) {
        accr = mfma16(a[kt], bb[jt][kt], accr);
        accz = mfma16(a[kt], bb[2 + jt][kt], accz);
        accn = mfma16(a[kt], bb[4 + jt][kt], accn);
      }
      const int j = jbase + jt * 16 + l15;
      #pragma unroll
      for (int reg = 0; reg < 4; ++reg) {
        const int m = quad * 4 + reg;
        const float xr = bfb2f(xwl[rb][m * GQ + j]);
        const float xz = bfb2f(xwl[rb][m * GQ + HQ + j]);
        const float xn = bfb2f(xwl[rb][m * GQ + 2 * HQ + j]);
        const float hold = bfb2f(h_lds[rb][m][j]);
        const float rg = sigmf(accr[reg] + xr);
        const float zg = sigmf(accz[reg] + xz);
        const float ng = tanh_fast(fmaf(rg, accn[reg], xn));
        const float hn = fmaf(zg, hold - ng, ng);
        h_lds[wb][m][j] = f2bfb(hn);
      }
    }
    __syncthreads();
  }

  // final out(99): h(100) lives in h_lds[LQ & 1] == h_lds[0]
  {
    short8 h0 = ld8(&h_lds[0][om][oc]);
    st8nt(&out[((size_t)(b0 + om) * LQ + (LQ - 1)) * HQ + oc], h0);
  }
}

// ------- fused attention: q/e dots + softmax + windowed context ------------
__global__ __launch_bounds__(256) void attn_fused_kernel(
    const u16* __restrict__ out1, const u16* __restrict__ out2,
    const float* __restrict__ attn_w,
    u16* __restrict__ c1, u16* __restrict__ c2) {
  const int b = blockIdx.x;
  const int br = blockIdx.y;
  const u16* out = br ? out2 : out1;
  u16* cb = br ? c2 : c1;
  const int tid = threadIdx.x;
  const int w = tid >> 6, lane = tid & 63;

  __shared__ u16 ol[LQ][HPAD];
  __shared__ float qv[LQ], ev[LQ];

  for (int idx = tid; idx < LQ * 32; idx += 256) {
    int row = idx >> 5, c8 = (idx & 31) * 8;
    *(short8*)&ol[row][c8] = ld8(&out[((size_t)b * LQ + row) * HQ + c8]);
  }
  __syncthreads();

  float aq[4], ae[4];
  #pragma unroll
  for (int jj = 0; jj < 4; ++jj) {
    aq[jj] = attn_w[lane + 64 * jj];
    ae[jj] = attn_w[HQ + lane + 64 * jj];
  }
  for (int l = w; l < LQ; l += 4) {
    float sq = 0.f, se = 0.f;
    #pragma unroll
    for (int jj = 0; jj < 4; ++jj) {
      float v = bfb2f(ol[l][lane + 64 * jj]);
      sq = fmaf(v, aq[jj], sq);
      se = fmaf(v, ae[jj], se);
    }
    #pragma unroll
    for (int o = 32; o > 0; o >>= 1) { sq += __shfl_down(sq, o); se += __shfl_down(se, o); }
    if (lane == 0) { qv[l] = sq; ev[l] = se; }
  }
  __syncthreads();

  for (int m = 0; m < MQ; ++m) {
    const float qq = qv[m + WINQ];
    float s[WINQ];
    float mx = -1e30f;
    #pragma unroll
    for (int k = 0; k < WINQ; ++k) { s[k] = qq + ev[m + k]; mx = fmaxf(mx, s[k]); }
    float sum = 0.f;
    #pragma unroll
    for (int k = 0; k < WINQ; ++k) { s[k] = __expf(s[k] - mx); sum += s[k]; }
    const float inv = rcpf(sum);
    float accv = 0.f;
    #pragma unroll
    for (int k = 0; k < WINQ; ++k)
      accv = fmaf(s[k], bfb2f(ol[m + k][tid]), accv);
    cb[((size_t)b * MQ + m) * HQ + tid] = f2bfb(accv * inv);
  }
}

// ---------------- fused FC via MFMA: [c | out] @ fcW^T + fcb ---------------
__global__ __launch_bounds__(256) void fc_mfma_kernel(
    const u16* __restrict__ c1, const u16* __restrict__ c2,
    const u16* __restrict__ o1, const u16* __restrict__ o2,
    const u16* __restrict__ fcw, const float* __restrict__ fcb,
    u16* __restrict__ f1, u16* __restrict__ f2) {
  const int br = blockIdx.y;
  const u16* cb = br ? c2 : c1;
  const u16* ob = br ? o2 : o1;
  u16* fo = br ? f2 : f1;
  const int i0 = blockIdx.x * 64;
  const int tid = threadIdx.x;
  const int w = tid >> 6, lane = tid & 63, l15 = lane & 15, quad = lane >> 4;

  __shared__ u16 a_lds[64][520];
  for (int g = tid; g < 64 * 64; g += 256) {        // 16B groups, K=512
    int rr = g >> 6, c8 = (g & 63) * 8;
    int gi = i0 + rr;
    int bb = gi / MQ, mm = gi - bb * MQ;
    const u16* src = (c8 < HQ) ? &cb[(size_t)gi * HQ + c8]
                               : &ob[((size_t)bb * LQ + mm + WINQ) * HQ + (c8 - HQ)];
    *(short8*)&a_lds[rr][c8] = ld8(src);
  }
  __syncthreads();

  for (int nt = 0; nt < 4; ++nt) {
    const int n0 = w * 64 + nt * 16;
    const u16* bp = fcw + (size_t)(n0 + l15) * 512 + quad * 8;
    short8 b[16];
    #pragma unroll
    for (int kt = 0; kt < 16; ++kt) b[kt] = ld8(bp + kt * 32);
    const float bias = fcb[n0 + l15];
    #pragma unroll
    for (int mt = 0; mt < 4; ++mt) {
      f32x4 acc = {bias, bias, bias, bias};
      #pragma unroll
      for (int kt = 0; kt < 16; ++kt) {
        short8 a = ld8(&a_lds[mt * 16 + l15][kt * 32 + quad * 8]);
        acc = mfma16(a, b[kt], acc);
      }
      #pragma unroll
      for (int reg = 0; reg < 4; ++reg)
        fo[(size_t)(i0 + mt * 16 + quad * 4 + reg) * HQ + n0 + l15] = f2bfb(acc[reg]);
    }
  }
}

// ---------------- final head -----------------------------------------------
__global__ __launch_bounds__(256) void final_kernel(
    const bf16* __restrict__ out1,
    const bf16* __restrict__ f1, const bf16* __restrict__ f2,
    const float* __restrict__ outW, const float* __restrict__ outb,
    float* __restrict__ dout) {
  const int wid = blockIdx.x * 4 + (threadIdx.x >> 6);
  const int lane = threadIdx.x & 63;
  const int b = wid / LQ, l = wid - b * LQ;
  const bf16* s1 = (l < WINQ) ? (out1 + ((size_t)b * LQ + l) * HQ)
                              : (f1 + ((size_t)b * MQ + (l - WINQ)) * HQ);
  int l2 = l + 10;  // D = 10
  if (l2 > LQ - 1) l2 = LQ - 1;
  const bf16* s2 = f2 + ((size_t)b * MQ + (l2 - WINQ)) * HQ;
  float s = 0.0f;
  #pragma unroll
  for (int jj = 0; jj < 4; ++jj) {
    int h = lane + jj * 64;
    s = fmaf(bf2f(s1[h]), outW[h], s);
    s = fmaf(bf2f(s2[h]), outW[HQ + h], s);
  }
  #pragma unroll
  for (int o = 32; o > 0; o >>= 1) s += __shfl_down(s, o);
  if (lane == 0) dout[wid] = sigmf(s + outb[0]);
}

extern "C" void kernel_launch(void* const* d_in, const int* in_sizes, int n_in,
                              void* d_out, int out_size, void* d_ws, size_t ws_size,
                              hipStream_t stream) {
  const float* x       = (const float*)d_in[0];
  const float* r1_Wih0 = (const float*)d_in[1];
  const float* r1_Whh0 = (const float*)d_in[2];
  const float* r1_bih0 = (const float*)d_in[3];
  const float* r1_bhh0 = (const float*)d_in[4];
  const float* r1_Wih1 = (const float*)d_in[5];
  const float* r1_Whh1 = (const float*)d_in[6];
  const float* r1_bih1 = (const float*)d_in[7];
  const float* r1_bhh1 = (const float*)d_in[8];
  const float* r2_Wih0 = (const float*)d_in[9];
  const float* r2_Whh0 = (const float*)d_in[10];
  const float* r2_bih0 = (const float*)d_in[11];
  const float* r2_bhh0 = (const float*)d_in[12];
  const float* r2_Wih1 = (const float*)d_in[13];
  const float* r2_Whh1 = (const float*)d_in[14];
  const float* r2_bih1 = (const float*)d_in[15];
  const float* r2_bhh1 = (const float*)d_in[16];
  const float* attn_w  = (const float*)d_in[17];
  const float* fc_W    = (const float*)d_in[18];
  const float* fc_b    = (const float*)d_in[19];
  const float* out_W   = (const float*)d_in[20];
  const float* out_b   = (const float*)d_in[21];

  char* p = (char*)d_ws;
  auto carve = [&](size_t bytes) {
    char* r = p;
    p += ((bytes + 255) / 256) * 256;
    return r;
  };
  const size_t WSZ = (size_t)GQ * HQ;            // 196608 (Whh/Wih1)
  const size_t XWR = (size_t)BQ * LQ * GQ;       // 39,321,600 per receiver
  const size_t SEQ = (size_t)BQ * LQ * HQ;       // 13,107,200
  const size_t FSEQ = (size_t)BQ * MQ * HQ;      // 12,451,840

  u16* whh0A = (u16*)carve(WSZ * 2);
  u16* whh0B = (u16*)carve(WSZ * 2);
  u16* whh1A = (u16*)carve(WSZ * 2);
  u16* whh1B = (u16*)carve(WSZ * 2);
  u16* wih1A = (u16*)carve(WSZ * 2);
  u16* wih1B = (u16*)carve(WSZ * 2);
  u16* fcwbf = (u16*)carve((size_t)HQ * 512 * 2);
  u16* xwbuf = (u16*)carve(XWR * 2 * 2);         // both receivers; reused L0 then L1
  u16* obuf  = (u16*)carve(SEQ * 2 * 2);         // L0 out; later overwritten by L1 out

  u16* xwA = xwbuf;
  u16* xwB = xwbuf + XWR;
  u16* oA  = obuf;
  u16* oB  = obuf + SEQ;
  // c/f alias the xw region (dead after layer-1 scan)
  u16* c1 = xwbuf;
  u16* c2 = c1 + FSEQ;
  u16* f1 = c2 + FSEQ;
  u16* f2 = f1 + FSEQ;

  // all weight conversions, one launch
  cvt7_kernel<<<dim3((WSZ / 4 + 255) / 256, 7), 256, 0, stream>>>(
      r1_Whh0, r2_Whh0, r1_Whh1, r2_Whh1, r1_Wih1, r2_Wih1, fc_W,
      whh0A, whh0B, whh1A, whh1B, wih1A, wih1B, fcwbf);

  // layer 0
  xw0_kernel<<<dim3(BQ * LQ / 16, 2), 256, 0, stream>>>(
      x, r1_Wih0, r1_bih0, r2_Wih0, r2_bih0, xwbuf);
  scan_mfma_kernel<<<dim3(BQ / 16, 2), 512, 0, stream>>>(
      xwA, xwB, whh0A, whh0B, r1_bhh0, r2_bhh0, oA, oB);
  // layer 1
  xw1_gemm_kernel<<<dim3(BQ * LQ / 64, 2), 256, 0, stream>>>(
      oA, oB, wih1A, wih1B, r1_bih1, r2_bih1, xwbuf);
  scan_mfma_kernel<<<dim3(BQ / 16, 2), 512, 0, stream>>>(
      xwA, xwB, whh1A, whh1B, r1_bhh1, r2_bhh1, oA, oB);

  // branch
  attn_fused_kernel<<<dim3(BQ, 2), 256, 0, stream>>>(oA, oB, attn_w, c1, c2);
  fc_mfma_kernel<<<dim3((BQ * MQ) / 64, 2), 256, 0, stream>>>(c1, c2, oA, oB, fcwbf, fc_b, f1, f2);
  final_kernel<<<(BQ * LQ) / 4, 256, 0, stream>>>(
      (const bf16*)oA, (const bf16*)f1, (const bf16*)f2, out_W, out_b, (float*)d_out);
}